// Round 5
// baseline (326.732 us; speedup 1.0000x reference)
//
#include <hip/hip_runtime.h>
#include <hip/hip_bf16.h>
#include <type_traits>

// ---------- types / helpers ----------
using bf16x8 = __attribute__((ext_vector_type(8))) short;   // 8 bf16 in 4 VGPRs
using f32x4  = __attribute__((ext_vector_type(4))) float;
using u16x8  = __attribute__((ext_vector_type(8))) unsigned short;
using u16x4  = __attribute__((ext_vector_type(4))) unsigned short;
using u32x4  = __attribute__((ext_vector_type(4))) unsigned int;

__device__ __forceinline__ float b2f(unsigned short u) {
    unsigned int x = ((unsigned int)u) << 16;
    return __builtin_bit_cast(float, x);
}
__device__ __forceinline__ unsigned short f2b(float f) {
    __hip_bfloat16 h = __float2bfloat16(f);   // RN
    return __builtin_bit_cast(unsigned short, h);
}

// exp2: bounded-domain scores, hardware v_exp_f32 either way
#if defined(__has_builtin)
#if __has_builtin(__builtin_amdgcn_exp2f)
#define EXP2F(x) __builtin_amdgcn_exp2f(x)
#else
#define EXP2F(x) exp2f(x)
#endif
#else
#define EXP2F(x) exp2f(x)
#endif

// async global->LDS, 16 B per lane; LDS dest is wave-uniform base + lane*16
__device__ __forceinline__ void async_copy16(const void* g, void* l) {
    __builtin_amdgcn_global_load_lds(
        (const __attribute__((address_space(1))) unsigned int*)g,
        (__attribute__((address_space(3))) unsigned int*)l, 16, 0, 0);
}

#define MFMA16(a, b, c) __builtin_amdgcn_mfma_f32_16x16x32_bf16(a, b, c, 0, 0, 0)

// raw barrier with compiler memory fence (no vmcnt/lgkmcnt drain)
#define BARRIER() do { asm volatile("" ::: "memory"); \
    __builtin_amdgcn_s_barrier(); asm volatile("" ::: "memory"); } while (0)
#define VMCNT6() asm volatile("s_waitcnt vmcnt(6)" ::: "memory")
#define VMCNT0() asm volatile("s_waitcnt vmcnt(0)" ::: "memory")

// ---------- f32 -> bf16 conversion (4 elems/thread) ----------
__global__ __launch_bounds__(256) void cvt_f32_to_bf16(
    const float* __restrict__ s, unsigned short* __restrict__ d, int n4)
{
    int i = blockIdx.x * blockDim.x + threadIdx.x;
    if (i >= n4) return;
    float4 v = ((const float4*)s)[i];
    ushort4 o;
    o.x = f2b(v.x); o.y = f2b(v.y); o.z = f2b(v.z); o.w = f2b(v.w);
    ((ushort4*)d)[i] = o;
}

// ---------- fused QKV GEMM, 256x256 8-phase template (T3+T4+T5) ----------
// [Q|K|V] = x @ [wq;wk;wv]^T.  M=4096, Ntot=3072, K=2048.
// Grid 16m x 12n = 192 blocks, 512 threads (8 waves), BK=64.
// LDS 128KB: 2 dbuf x (A,B) x 256x64 bf16, staged in 128-row halves
// (A-low rows 0-127, A-high 128-255; same for B). Wave m-mapping:
// wfm=(w>>2)*64; wave's two m-halves are {wfm..wfm+63} (in A-low, read P1)
// and {128+wfm..} (in A-high, read P3) -- READ HALF MUST MATCH STAGE HALF
// (R3 bug: wfm=(w>>2)*128 made P3 read rows 64-127 after P2 re-staged them).
// Wave n: wfn=(w&3)*64; B reads confined to one half, done by P2.
// 8 phases per 2 K-tiles: {ds_read subtile | stage 1 half-tile} -> s_barrier
// -> 16 MFMA (setprio) -> s_barrier. vmcnt(6) ONLY at P4/P8:
//  P1: ds A-lo,B(b0)  stage b1.Ahi(u+1)   P5: ds A-lo,B(b1)  stage b0.Ahi(u+2)
//  P2: ds B(b0)       stage b0.Alo(u+2)   P6: ds B(b1)       stage b1.Alo(u+3)
//  P3: ds A-hi(b0)    stage b0.Blo(u+2)   P7: ds A-hi(b1)    stage b1.Blo(u+3)
//  P4: vmcnt6 [lands ALL b1(u+1)]         P8: vmcnt6 [lands ALL b0(u+2)]
//      stage b0.Bhi(u+2)                      stage b1.Bhi(u+3)
// Invariant at iter entry: outstanding <= 6 = {b1.Alo,Blo,Bhi(u+1)}; all
// older loads (incl. b0(u) full) landed. Every region re-staged >=1 closing
// barrier after its last read.
__global__ __launch_bounds__(512, 2) void qkv_gemm(
    const unsigned short* __restrict__ A,    // M x 2048
    const unsigned short* __restrict__ Wq,   // 2048 x 2048
    const unsigned short* __restrict__ Wk,   // 512 x 2048
    const unsigned short* __restrict__ Wv,   // 512 x 2048
    unsigned short* __restrict__ Q,          // M x 2048
    unsigned short* __restrict__ Kk,         // M x 512
    unsigned short* __restrict__ V)          // M x 512
{
    const int K = 2048;
    __shared__ unsigned short ldsA[2][256 * 64];
    __shared__ unsigned short ldsB[2][256 * 64];

    int tid  = threadIdx.x;
    int w    = tid >> 6;           // 0..7
    int lane = tid & 63;
    int idx  = lane & 15;
    int quad = lane >> 4;
    int srow   = lane >> 3;
    int schunk = (lane & 7) ^ srow;

    int wfm = (w >> 2) * 64;       // wave m-offset within each 128-row half
    int wfn = (w & 3) * 64;        // wave n-offset

    // XCD-contiguous swizzle (192 % 8 == 0, bijective)
    int bid = (blockIdx.x & 7) * 24 + (blockIdx.x >> 3);
    int bm = bid / 12;
    int bn = bid - bm * 12;
    int m0 = bm * 256;

    const unsigned short* Bt;
    unsigned short* C;
    int Nc, n0;
    if (bn < 8)       { Bt = Wq + (size_t)bn * 256 * K;        C = Q;  Nc = 2048; n0 = bn * 256; }
    else if (bn < 10) { Bt = Wk + (size_t)(bn - 8) * 256 * K;  C = Kk; Nc = 512;  n0 = (bn - 8) * 256; }
    else              { Bt = Wv + (size_t)(bn - 10) * 256 * K; C = V;  Nc = 512;  n0 = (bn - 10) * 256; }

    const unsigned short* Ab = A + (size_t)m0 * K;

    f32x4 acc[8][4];
    #pragma unroll
    for (int mf = 0; mf < 8; ++mf)
        #pragma unroll
        for (int nf = 0; nf < 4; ++nf) acc[mf][nf] = (f32x4){0.f, 0.f, 0.f, 0.f};

    bf16x8 a[4][2], b0[2][2], b1[2][2];

    // stage one 128x64 half-tile (2 global_load_lds / thread)
    auto STAGE = [&](const unsigned short* __restrict__ G, int rb, int kc,
                     unsigned short* dst) {
        #pragma unroll
        for (int i = 0; i < 2; ++i) {
            int R = (w * 2 + i) * 8;
            async_copy16(G + (size_t)(rb + R + srow) * K + kc + schunk * 8,
                         dst + (size_t)R * 64);
        }
    };
    // mh selects the 128-row staging half; wave reads rows mh*128+wfm+...
    auto LDA = [&](int d, int mh) {
        #pragma unroll
        for (int mi = 0; mi < 4; ++mi) {
            int r = mh * 128 + wfm + mi * 16 + idx;
            #pragma unroll
            for (int ks = 0; ks < 2; ++ks)
                a[mi][ks] = *(const bf16x8*)&ldsA[d][r * 64 + (((ks * 4 + quad) ^ (r & 7)) << 3)];
        }
    };
    auto LDB0 = [&](int d, int nh) {
        #pragma unroll
        for (int nj = 0; nj < 2; ++nj) {
            int r = wfn + nh * 32 + nj * 16 + idx;
            #pragma unroll
            for (int ks = 0; ks < 2; ++ks)
                b0[nj][ks] = *(const bf16x8*)&ldsB[d][r * 64 + (((ks * 4 + quad) ^ (r & 7)) << 3)];
        }
    };
    auto LDB1 = [&](int d, int nh) {
        #pragma unroll
        for (int nj = 0; nj < 2; ++nj) {
            int r = wfn + nh * 32 + nj * 16 + idx;
            #pragma unroll
            for (int ks = 0; ks < 2; ++ks)
                b1[nj][ks] = *(const bf16x8*)&ldsB[d][r * 64 + (((ks * 4 + quad) ^ (r & 7)) << 3)];
        }
    };
    auto MM0 = [&](int mh, int nh) {   // quadrant with b0
        __builtin_amdgcn_s_setprio(1);
        #pragma unroll
        for (int mi = 0; mi < 4; ++mi)
            #pragma unroll
            for (int nj = 0; nj < 2; ++nj)
                #pragma unroll
                for (int ks = 0; ks < 2; ++ks)
                    acc[mh * 4 + mi][nh * 2 + nj] =
                        MFMA16(a[mi][ks], b0[nj][ks], acc[mh * 4 + mi][nh * 2 + nj]);
        __builtin_amdgcn_s_setprio(0);
    };
    auto MM1 = [&](int mh, int nh) {   // quadrant with b1
        __builtin_amdgcn_s_setprio(1);
        #pragma unroll
        for (int mi = 0; mi < 4; ++mi)
            #pragma unroll
            for (int nj = 0; nj < 2; ++nj)
                #pragma unroll
                for (int ks = 0; ks < 2; ++ks)
                    acc[mh * 4 + mi][nh * 2 + nj] =
                        MFMA16(a[mi][ks], b1[nj][ks], acc[mh * 4 + mi][nh * 2 + nj]);
        __builtin_amdgcn_s_setprio(0);
    };

    // ---- prologue: tile0 full into buf0, tile1 Alo/Blo/Bhi into buf1 ----
    STAGE(Ab, 0,   0,  &ldsA[0][0]);
    STAGE(Ab, 128, 0,  &ldsA[0][128 * 64]);
    STAGE(Bt, 0,   0,  &ldsB[0][0]);
    STAGE(Bt, 128, 0,  &ldsB[0][128 * 64]);
    STAGE(Ab, 0,   64, &ldsA[1][0]);
    STAGE(Bt, 0,   64, &ldsB[1][0]);
    STAGE(Bt, 128, 64, &ldsB[1][128 * 64]);
    VMCNT6();          // tile0 (8 oldest loads) landed; 6 outstanding
    BARRIER();

    // ---- main loop: 15 iters, tiles u=2it, u+1; stages u+2, u+3 (max 31) ----
    for (int it = 0; it < 15; ++it) {
        int u = 2 * it;
        // P1
        LDA(0, 0); LDB0(0, 0);
        STAGE(Ab, 128, (u + 1) * 64, &ldsA[1][128 * 64]);
        BARRIER(); MM0(0, 0); BARRIER();
        // P2
        LDB1(0, 1);
        STAGE(Ab, 0, (u + 2) * 64, &ldsA[0][0]);
        BARRIER(); MM1(0, 1); BARRIER();
        // P3
        LDA(0, 1);
        STAGE(Bt, 0, (u + 2) * 64, &ldsB[0][0]);
        BARRIER(); MM1(1, 1); BARRIER();
        // P4
        STAGE(Bt, 128, (u + 2) * 64, &ldsB[0][128 * 64]);
        VMCNT6();          // all of buf1 (tile u+1) landed
        BARRIER(); MM0(1, 0); BARRIER();
        // P5
        LDA(1, 0); LDB0(1, 0);
        STAGE(Ab, 128, (u + 2) * 64, &ldsA[0][128 * 64]);
        BARRIER(); MM0(0, 0); BARRIER();
        // P6
        LDB1(1, 1);
        STAGE(Ab, 0, (u + 3) * 64, &ldsA[1][0]);
        BARRIER(); MM1(0, 1); BARRIER();
        // P7
        LDA(1, 1);
        STAGE(Bt, 0, (u + 3) * 64, &ldsB[1][0]);
        BARRIER(); MM1(1, 1); BARRIER();
        // P8
        STAGE(Bt, 128, (u + 3) * 64, &ldsB[1][128 * 64]);
        VMCNT6();          // all of buf0 (tile u+2) landed
        BARRIER(); MM0(1, 0); BARRIER();
    }

    // ---- epilogue: tiles 30 (buf0), 31 (buf1); only stage left: b1.Ahi(31) ----
    LDA(0, 0); LDB0(0, 0);
    STAGE(Ab, 128, 31 * 64, &ldsA[1][128 * 64]);
    BARRIER(); MM0(0, 0); BARRIER();
    LDB1(0, 1);
    BARRIER(); MM1(0, 1); BARRIER();
    LDA(0, 1);
    BARRIER(); MM1(1, 1); BARRIER();
    VMCNT0();
    BARRIER(); MM0(1, 0); BARRIER();
    LDA(1, 0); LDB0(1, 0);
    BARRIER(); MM0(0, 0); BARRIER();
    LDB1(1, 1);
    BARRIER(); MM1(0, 1); BARRIER();
    LDA(1, 1);
    BARRIER(); MM1(1, 1); BARRIER();
    MM0(1, 0);

    // ---- C write: row half from mf>>2, offset wfm within half ----
    #pragma unroll
    for (int mf = 0; mf < 8; ++mf) {
        #pragma unroll
        for (int r = 0; r < 4; ++r) {
            size_t row = (size_t)(m0 + (mf >> 2) * 128 + wfm + (mf & 3) * 16 + quad * 4 + r);
            #pragma unroll
            for (int nf = 0; nf < 4; ++nf) {
                int col = n0 + wfn + nf * 16 + idx;
                C[row * Nc + col] = f2b(acc[mf][nf][r]);
            }
        }
    }
}

// ---------- tiled GEMM: C[M,N] = A[M,K] * Bt[N,K]^T (wo projection, dbuf) ----------
__device__ __forceinline__ void g_stage(
    const unsigned short* __restrict__ A, const unsigned short* __restrict__ Bt,
    unsigned short* As, unsigned short* Bs,
    int k0, int K, int w, int srow, int schunk)
{
    #pragma unroll
    for (int i = 0; i < 4; ++i) {
        int cb = w * 4 + i;
        size_t goff = (size_t)(cb * 8 + srow) * K + k0 + schunk * 8;
        async_copy16(A  + goff, &As[cb * 512]);
        async_copy16(Bt + goff, &Bs[cb * 512]);
    }
}
__device__ __forceinline__ void g_compute(
    const unsigned short* As, const unsigned short* Bs,
    f32x4 (&acc)[4][4], int wm, int wn, int idx, int quad)
{
    #pragma unroll
    for (int ks = 0; ks < 2; ++ks) {
        bf16x8 af[4], bfr[4];
        #pragma unroll
        for (int mi = 0; mi < 4; ++mi) {
            int row = wm + mi * 16 + idx;
            af[mi] = *(const bf16x8*)&As[row * 64 + (((ks * 4 + quad) ^ (row & 7)) * 8)];
        }
        #pragma unroll
        for (int ni = 0; ni < 4; ++ni) {
            int row = wn + ni * 16 + idx;
            bfr[ni] = *(const bf16x8*)&Bs[row * 64 + (((ks * 4 + quad) ^ (row & 7)) * 8)];
        }
        #pragma unroll
        for (int mi = 0; mi < 4; ++mi)
            #pragma unroll
            for (int ni = 0; ni < 4; ++ni)
                acc[mi][ni] = MFMA16(af[mi], bfr[ni], acc[mi][ni]);
    }
}

template <typename OutT>
__global__ __launch_bounds__(256) void gemm_tile(
    const unsigned short* __restrict__ A,
    const unsigned short* __restrict__ Bt,
    OutT* __restrict__ C,
    int M, int N, int K)
{
    constexpr int BK = 64;
    __shared__ unsigned short As0[128 * BK];
    __shared__ unsigned short Bs0[128 * BK];
    __shared__ unsigned short As1[128 * BK];
    __shared__ unsigned short Bs1[128 * BK];

    int tid  = threadIdx.x;
    int w    = tid >> 6;
    int lane = tid & 63;
    int idx  = lane & 15;
    int quad = lane >> 4;
    int wm   = (w >> 1) * 64;
    int wn   = (w & 1) * 64;

    int tilesN = N / 128;
    int bm = blockIdx.x / tilesN;
    int bn = blockIdx.x - bm * tilesN;
    int m0 = bm * 128, n0 = bn * 128;

    const unsigned short* Ab = A  + (size_t)m0 * K;
    const unsigned short* Bb = Bt + (size_t)n0 * K;

    int srow   = lane >> 3;
    int schunk = (lane & 7) ^ srow;

    f32x4 acc[4][4];
    #pragma unroll
    for (int mi = 0; mi < 4; ++mi)
        #pragma unroll
        for (int ni = 0; ni < 4; ++ni) acc[mi][ni] = (f32x4){0.f, 0.f, 0.f, 0.f};

    g_stage(Ab, Bb, As0, Bs0, 0, K, w, srow, schunk);
    __syncthreads();

    for (int k0 = 0; k0 < K; k0 += 2 * BK) {
        if (k0 + BK < K)
            g_stage(Ab, Bb, As1, Bs1, k0 + BK, K, w, srow, schunk);
        g_compute(As0, Bs0, acc, wm, wn, idx, quad);
        __syncthreads();
        if (k0 + 2 * BK < K)
            g_stage(Ab, Bb, As0, Bs0, k0 + 2 * BK, K, w, srow, schunk);
        g_compute(As1, Bs1, acc, wm, wn, idx, quad);
        __syncthreads();
    }

    #pragma unroll
    for (int mi = 0; mi < 4; ++mi) {
        #pragma unroll
        for (int r = 0; r < 4; ++r) {
            size_t row = (size_t)(m0 + wm + mi * 16 + quad * 4 + r);
            #pragma unroll
            for (int ni = 0; ni < 4; ++ni) {
                int col = n0 + wn + ni * 16 + idx;
                if constexpr (std::is_same_v<OutT, float>) {
                    C[row * N + col] = acc[mi][ni][r];
                } else {
                    C[row * N + col] = f2b(acc[mi][ni][r]);
                }
            }
        }
    }
}

// ---------- RoPE (in-place on bf16, f32 freqs; oscale folds attn scale into q) ----------
__global__ __launch_bounds__(256) void rope_kernel(
    unsigned short* __restrict__ x,
    const float* __restrict__ cs,
    const float* __restrict__ sn,
    int H, int total, float oscale)
{
    int e = blockIdx.x * blockDim.x + threadIdx.x;
    if (e >= total) return;
    int i = e & 63;
    int s = (e / (64 * H)) & 2047;   // S = 2048
    float xr = b2f(x[2 * e]);
    float xi = b2f(x[2 * e + 1]);
    float c  = cs[s * 64 + i];
    float sv = sn[s * 64 + i];
    x[2 * e]     = f2b((xr * c - xi * sv) * oscale);
    x[2 * e + 1] = f2b((xr * sv + xi * c) * oscale);
}

// ---------- MFMA flash attention v5: 512 blocks x 512 threads ----------
__global__ __launch_bounds__(512, 4) void flash_attn(
    const unsigned short* __restrict__ qg,
    const unsigned short* __restrict__ kk,
    const unsigned short* __restrict__ vv,
    unsigned short* __restrict__ out)
{
    const int S = 2048;
    int bid = blockIdx.x;
    int qp  = bid & 15;
    int bh  = bid >> 4;            // b*16 + h
    int h   = bh & 15;
    int b   = bh >> 4;
    int kvh = h >> 2;

    int p   = b ? (15 - qp) : qp;

    int tid  = threadIdx.x;
    int w    = tid >> 6;           // 0..7
    int lane = tid & 63;
    int idx  = lane & 15;
    int quad = lane >> 4;

    int qt  = 2 * p + (w >> 2);    // waves 0-3: tile 2p, waves 4-7: tile 2p+1
    int q0  = qt * 64;
    int wq0 = q0 + (w & 3) * 16;
    int qr  = wq0 + idx;

    __shared__ unsigned short Ks[32 * 128];   // XOR-chunk-swizzled rows
    __shared__ unsigned short Vt[128 * 40];   // V^T, key-pair permuted, pad 40, col-slot swizzled

    const unsigned short* kbase = kk + ((size_t)b * S * 4 + kvh) * 128;
    const unsigned short* vbase = vv + ((size_t)b * S * 4 + kvh) * 128;

    bf16x8 qf[4];
    {
        const unsigned short* qpp =
            qg + ((size_t)((b * S + wq0 + idx) * 16 + h)) * 128 + quad * 8;
        #pragma unroll
        for (int ko = 0; ko < 4; ++ko)
            qf[ko] = *(const bf16x8*)(qpp + ko * 32);
    }

    f32x4 acc[8];
    #pragma unroll
    for (int n = 0; n < 8; ++n) acc[n] = (f32x4){0.f, 0.f, 0.f, 0.f};
    float lsum = 0.f;

    int dp = (tid & 63) * 2;
    int jb = (tid >> 6) & 3;
    int ih = (tid >> 8) * 4;       // i-half: 0..3 or 4..7

    int vcol = (((jb ^ ((dp >> 3) & 3)) << 3) + ih);

    int nt = 4 * p + 4;

    for (int t = 0; t < nt; ++t) {
        {
            int key = w * 4 + (lane >> 4);
            int sc  = (lane & 15) ^ (key & 7);
            async_copy16(kbase + ((size_t)(t * 32 + key)) * 512 + sc * 8,
                         &Ks[w * 512]);
        }
        {
            const unsigned short* vc = vbase + ((size_t)(t * 32 + jb * 4)) * 512 + dp;
            unsigned int ld[4];
            #pragma unroll
            for (int i = 0; i < 4; ++i) {
                int ii  = ih + i;
                int key = (ii >> 1) + 16 * (ii & 1);
                ld[i] = *(const unsigned int*)(vc + key * 512);
            }
            u16x4 lo, hi;
            #pragma unroll
            for (int i = 0; i < 4; ++i) {
                lo[i] = (unsigned short)ld[i];
                hi[i] = (unsigned short)(ld[i] >> 16);
            }
            *(u16x4*)&Vt[dp * 40 + vcol]       = lo;
            *(u16x4*)&Vt[(dp + 1) * 40 + vcol] = hi;
        }
        __syncthreads();

        if (t * 32 <= wq0 + 15) {
            f32x4 s0 = {0.f,0.f,0.f,0.f}, s1 = {0.f,0.f,0.f,0.f};
            #pragma unroll
            for (int ko = 0; ko < 4; ++ko) {
                int kc = ko * 4 + quad;
                bf16x8 kf0 = *(const bf16x8*)&Ks[idx * 128 + ((kc ^ (idx & 7)) * 8)];
                bf16x8 kf1 = *(const bf16x8*)&Ks[(16 + idx) * 128 + ((kc ^ (idx & 7)) * 8)];
                s0 = MFMA16(kf0, qf[ko], s0);
                s1 = MFMA16(kf1, qf[ko], s1);
            }
            unsigned int pk[4];
            if (t * 32 + 31 <= wq0) {
                #pragma unroll
                for (int r = 0; r < 4; ++r) {
                    float p0 = EXP2F(s0[r]);
                    float p1 = EXP2F(s1[r]);
                    lsum += p0 + p1;
                    pk[r] = (unsigned int)f2b(p0) | ((unsigned int)f2b(p1) << 16);
                }
            } else {
                int L = qr - t * 32;
                #pragma unroll
                for (int r = 0; r < 4; ++r) {
                    int kl = quad * 4 + r;
                    float p0 = (kl      <= L) ? EXP2F(s0[r]) : 0.f;
                    float p1 = (kl + 16 <= L) ? EXP2F(s1[r]) : 0.f;
                    lsum += p0 + p1;
                    pk[r] = (unsigned int)f2b(p0) | ((unsigned int)f2b(p1) << 16);
                }
            }
            u32x4 pku = {pk[0], pk[1], pk[2], pk[3]};
            bf16x8 pf = __builtin_bit_cast(bf16x8, pku);
            #pragma unroll
            for (int n = 0; n < 8; ++n) {
                int rr = n * 16 + idx;
                bf16x8 vf = *(const bf16x8*)&Vt[rr * 40 + ((quad ^ ((rr >> 3) & 3)) << 3)];
                acc[n] = MFMA16(vf, pf, acc[n]);
            }
        }
        __syncthreads();
    }

    lsum += __shfl_xor(lsum, 16);
    lsum += __shfl_xor(lsum, 32);
    float inv = 1.f / lsum;
    size_t rowb = (size_t)(b * S + wq0 + idx) * 2048 + h * 128;
    #pragma unroll
    for (int n = 0; n < 8; ++n) {
        ushort4 o;
        o.x = f2b(acc[n][0] * inv);
        o.y = f2b(acc[n][1] * inv);
        o.z = f2b(acc[n][2] * inv);
        o.w = f2b(acc[n][3] * inv);
        *(ushort4*)&out[rowb + n * 16 + quad * 4] = o;
    }
}

// ---------- launch ----------
extern "C" void kernel_launch(void* const* d_in, const int* in_sizes, int n_in,
                              void* d_out, int out_size, void* d_ws, size_t ws_size,
                              hipStream_t stream)
{
    const float* x  = (const float*)d_in[0];
    const float* fc = (const float*)d_in[1];
    const float* fs = (const float*)d_in[2];
    const float* wq = (const float*)d_in[3];
    const float* wk = (const float*)d_in[4];
    const float* wv = (const float*)d_in[5];
    const float* wo = (const float*)d_in[6];
    float* out = (float*)d_out;

    const int B = 2, S = 2048, D = 2048, KV = 512;
    const int M = B * S;                 // 4096

    unsigned short* ws  = (unsigned short*)d_ws;
    unsigned short* xb  = ws;                         // 4096*2048
    unsigned short* wqb = xb  + (size_t)M * D;        // 2048*2048
    unsigned short* wkb = wqb + (size_t)D * D;        // 512*2048
    unsigned short* wvb = wkb + (size_t)KV * D;       // 512*2048
    unsigned short* wob = wvb + (size_t)KV * D;       // 2048*2048
    unsigned short* qb  = wob + (size_t)D * D;        // 4096*2048
    unsigned short* kb  = qb  + (size_t)M * D;        // 4096*512
    unsigned short* vb  = kb  + (size_t)M * KV;       // 4096*512
    unsigned short* ao  = vb  + (size_t)M * KV;       // 4096*2048

    cvt_f32_to_bf16<<<dim3((M * D / 4) / 256), dim3(256), 0, stream>>>(x,  xb,  M * D / 4);
    cvt_f32_to_bf16<<<dim3((D * D / 4) / 256), dim3(256), 0, stream>>>(wq, wqb, D * D / 4);
    cvt_f32_to_bf16<<<dim3((KV * D / 4) / 256), dim3(256), 0, stream>>>(wk, wkb, KV * D / 4);
    cvt_f32_to_bf16<<<dim3((KV * D / 4) / 256), dim3(256), 0, stream>>>(wv, wvb, KV * D / 4);
    cvt_f32_to_bf16<<<dim3((D * D / 4) / 256), dim3(256), 0, stream>>>(wo, wob, D * D / 4);

    // fused QKV projection: 16 m-tiles x 12 n-tiles = 192 blocks, 512 thr
    qkv_gemm<<<dim3(192), dim3(512), 0, stream>>>(xb, wqb, wkb, wvb, qb, kb, vb);

    int qpairs = B * S * 16 * 64;
    int kpairs = B * S * 4 * 64;
    const float c2 = 0.12752584f;   // (1/sqrt(128)) * log2(e), folded into q
    rope_kernel<<<dim3(qpairs / 256), dim3(256), 0, stream>>>(qb, fc, fs, 16, qpairs, c2);
    rope_kernel<<<dim3(kpairs / 256), dim3(256), 0, stream>>>(kb, fc, fs, 4, kpairs, 1.0f);

    // flash attention: 512 blocks x 512 threads (8 waves, adjacent tile-pair)
    flash_attn<<<dim3(512), dim3(512), 0, stream>>>(qb, kb, vb, ao);

    gemm_tile<float><<<dim3((M / 128) * (D / 128)), dim3(256), 0, stream>>>(ao, wob, out, M, D, D);
}

// Round 7
// 317.576 us; speedup vs baseline: 1.0288x; 1.0288x over previous
//
#include <hip/hip_runtime.h>
#include <hip/hip_bf16.h>
#include <type_traits>

// ---------- types / helpers ----------
using bf16x8 = __attribute__((ext_vector_type(8))) short;   // 8 bf16 in 4 VGPRs
using f32x4  = __attribute__((ext_vector_type(4))) float;
using u16x8  = __attribute__((ext_vector_type(8))) unsigned short;
using u16x4  = __attribute__((ext_vector_type(4))) unsigned short;
using u32x4  = __attribute__((ext_vector_type(4))) unsigned int;

__device__ __forceinline__ float b2f(unsigned short u) {
    unsigned int x = ((unsigned int)u) << 16;
    return __builtin_bit_cast(float, x);
}
__device__ __forceinline__ unsigned short f2b(float f) {
    __hip_bfloat16 h = __float2bfloat16(f);   // RN
    return __builtin_bit_cast(unsigned short, h);
}

// exp2: bounded-domain scores, hardware v_exp_f32 either way
#if defined(__has_builtin)
#if __has_builtin(__builtin_amdgcn_exp2f)
#define EXP2F(x) __builtin_amdgcn_exp2f(x)
#else
#define EXP2F(x) exp2f(x)
#endif
#else
#define EXP2F(x) exp2f(x)
#endif

// async global->LDS, 16 B per lane; LDS dest is wave-uniform base + lane*16
__device__ __forceinline__ void async_copy16(const void* g, void* l) {
    __builtin_amdgcn_global_load_lds(
        (const __attribute__((address_space(1))) unsigned int*)g,
        (__attribute__((address_space(3))) unsigned int*)l, 16, 0, 0);
}

#define MFMA16(a, b, c) __builtin_amdgcn_mfma_f32_16x16x32_bf16(a, b, c, 0, 0, 0)

// raw barrier with compiler memory fence (no vmcnt/lgkmcnt drain)
#define BARRIER() do { asm volatile("" ::: "memory"); \
    __builtin_amdgcn_s_barrier(); asm volatile("" ::: "memory"); } while (0)
#define VMCNT6() asm volatile("s_waitcnt vmcnt(6)" ::: "memory")
#define VMCNT0() asm volatile("s_waitcnt vmcnt(0)" ::: "memory")

// ---------- f32 -> bf16 conversion (4 elems/thread) ----------
__global__ __launch_bounds__(256) void cvt_f32_to_bf16(
    const float* __restrict__ s, unsigned short* __restrict__ d, int n4)
{
    int i = blockIdx.x * blockDim.x + threadIdx.x;
    if (i >= n4) return;
    float4 v = ((const float4*)s)[i];
    ushort4 o;
    o.x = f2b(v.x); o.y = f2b(v.y); o.z = f2b(v.z); o.w = f2b(v.w);
    ((ushort4*)d)[i] = o;
}

// ---------- fused QKV GEMM, 256x256 8-phase template (T3+T4+T5) ----------
// [Q|K|V] = x @ [wq;wk;wv]^T.  M=4096, Ntot=3072, K=2048.
// Grid 16m x 12n = 192 blocks, 512 threads (8 waves), BK=64.
// LDS 128KB: 2 dbuf x (A,B) x 256x64 bf16, staged in 128-row halves.
// Wave m: wfm=(w>>2)*64; wave's m-halves are {wfm..} (A-low, read P1) and
// {128+wfm..} (A-high, read P3) -- read half matches stage half.
// 8 phases per 2 K-tiles; vmcnt(6) ONLY at P4/P8 (3 half-tiles in flight).
__global__ __launch_bounds__(512, 2) void qkv_gemm(
    const unsigned short* __restrict__ A,    // M x 2048
    const unsigned short* __restrict__ Wq,   // 2048 x 2048
    const unsigned short* __restrict__ Wk,   // 512 x 2048
    const unsigned short* __restrict__ Wv,   // 512 x 2048
    unsigned short* __restrict__ Q,          // M x 2048
    unsigned short* __restrict__ Kk,         // M x 512
    unsigned short* __restrict__ V)          // M x 512
{
    const int K = 2048;
    __shared__ unsigned short ldsA[2][256 * 64];
    __shared__ unsigned short ldsB[2][256 * 64];

    int tid  = threadIdx.x;
    int w    = tid >> 6;           // 0..7
    int lane = tid & 63;
    int idx  = lane & 15;
    int quad = lane >> 4;
    int srow   = lane >> 3;
    int schunk = (lane & 7) ^ srow;

    int wfm = (w >> 2) * 64;       // wave m-offset within each 128-row half
    int wfn = (w & 3) * 64;        // wave n-offset

    // XCD-contiguous swizzle (192 % 8 == 0, bijective)
    int bid = (blockIdx.x & 7) * 24 + (blockIdx.x >> 3);
    int bm = bid / 12;
    int bn = bid - bm * 12;
    int m0 = bm * 256;

    const unsigned short* Bt;
    unsigned short* C;
    int Nc, n0;
    if (bn < 8)       { Bt = Wq + (size_t)bn * 256 * K;        C = Q;  Nc = 2048; n0 = bn * 256; }
    else if (bn < 10) { Bt = Wk + (size_t)(bn - 8) * 256 * K;  C = Kk; Nc = 512;  n0 = (bn - 8) * 256; }
    else              { Bt = Wv + (size_t)(bn - 10) * 256 * K; C = V;  Nc = 512;  n0 = (bn - 10) * 256; }

    const unsigned short* Ab = A + (size_t)m0 * K;

    f32x4 acc[8][4];
    #pragma unroll
    for (int mf = 0; mf < 8; ++mf)
        #pragma unroll
        for (int nf = 0; nf < 4; ++nf) acc[mf][nf] = (f32x4){0.f, 0.f, 0.f, 0.f};

    bf16x8 a[4][2], b0[2][2], b1[2][2];

    // stage one 128x64 half-tile (2 global_load_lds / thread)
    auto STAGE = [&](const unsigned short* __restrict__ G, int rb, int kc,
                     unsigned short* dst) {
        #pragma unroll
        for (int i = 0; i < 2; ++i) {
            int R = (w * 2 + i) * 8;
            async_copy16(G + (size_t)(rb + R + srow) * K + kc + schunk * 8,
                         dst + (size_t)R * 64);
        }
    };
    // mh selects the 128-row staging half; wave reads rows mh*128+wfm+...
    auto LDA = [&](int d, int mh) {
        #pragma unroll
        for (int mi = 0; mi < 4; ++mi) {
            int r = mh * 128 + wfm + mi * 16 + idx;
            #pragma unroll
            for (int ks = 0; ks < 2; ++ks)
                a[mi][ks] = *(const bf16x8*)&ldsA[d][r * 64 + (((ks * 4 + quad) ^ (r & 7)) << 3)];
        }
    };
    auto LDB0 = [&](int d, int nh) {
        #pragma unroll
        for (int nj = 0; nj < 2; ++nj) {
            int r = wfn + nh * 32 + nj * 16 + idx;
            #pragma unroll
            for (int ks = 0; ks < 2; ++ks)
                b0[nj][ks] = *(const bf16x8*)&ldsB[d][r * 64 + (((ks * 4 + quad) ^ (r & 7)) << 3)];
        }
    };
    auto LDB1 = [&](int d, int nh) {
        #pragma unroll
        for (int nj = 0; nj < 2; ++nj) {
            int r = wfn + nh * 32 + nj * 16 + idx;
            #pragma unroll
            for (int ks = 0; ks < 2; ++ks)
                b1[nj][ks] = *(const bf16x8*)&ldsB[d][r * 64 + (((ks * 4 + quad) ^ (r & 7)) << 3)];
        }
    };
    auto MM0 = [&](int mh, int nh) {   // quadrant with b0
        __builtin_amdgcn_s_setprio(1);
        #pragma unroll
        for (int mi = 0; mi < 4; ++mi)
            #pragma unroll
            for (int nj = 0; nj < 2; ++nj)
                #pragma unroll
                for (int ks = 0; ks < 2; ++ks)
                    acc[mh * 4 + mi][nh * 2 + nj] =
                        MFMA16(a[mi][ks], b0[nj][ks], acc[mh * 4 + mi][nh * 2 + nj]);
        __builtin_amdgcn_s_setprio(0);
    };
    auto MM1 = [&](int mh, int nh) {   // quadrant with b1
        __builtin_amdgcn_s_setprio(1);
        #pragma unroll
        for (int mi = 0; mi < 4; ++mi)
            #pragma unroll
            for (int nj = 0; nj < 2; ++nj)
                #pragma unroll
                for (int ks = 0; ks < 2; ++ks)
                    acc[mh * 4 + mi][nh * 2 + nj] =
                        MFMA16(a[mi][ks], b1[nj][ks], acc[mh * 4 + mi][nh * 2 + nj]);
        __builtin_amdgcn_s_setprio(0);
    };

    // ---- prologue: tile0 full into buf0, tile1 Alo/Blo/Bhi into buf1 ----
    STAGE(Ab, 0,   0,  &ldsA[0][0]);
    STAGE(Ab, 128, 0,  &ldsA[0][128 * 64]);
    STAGE(Bt, 0,   0,  &ldsB[0][0]);
    STAGE(Bt, 128, 0,  &ldsB[0][128 * 64]);
    STAGE(Ab, 0,   64, &ldsA[1][0]);
    STAGE(Bt, 0,   64, &ldsB[1][0]);
    STAGE(Bt, 128, 64, &ldsB[1][128 * 64]);
    VMCNT6();          // tile0 (8 oldest loads) landed; 6 outstanding
    BARRIER();

    // ---- main loop: 15 iters, tiles u=2it, u+1; stages u+2, u+3 (max 31) ----
    for (int it = 0; it < 15; ++it) {
        int u = 2 * it;
        // P1
        LDA(0, 0); LDB0(0, 0);
        STAGE(Ab, 128, (u + 1) * 64, &ldsA[1][128 * 64]);
        BARRIER(); MM0(0, 0); BARRIER();
        // P2
        LDB1(0, 1);
        STAGE(Ab, 0, (u + 2) * 64, &ldsA[0][0]);
        BARRIER(); MM1(0, 1); BARRIER();
        // P3
        LDA(0, 1);
        STAGE(Bt, 0, (u + 2) * 64, &ldsB[0][0]);
        BARRIER(); MM1(1, 1); BARRIER();
        // P4
        STAGE(Bt, 128, (u + 2) * 64, &ldsB[0][128 * 64]);
        VMCNT6();          // all of buf1 (tile u+1) landed
        BARRIER(); MM0(1, 0); BARRIER();
        // P5
        LDA(1, 0); LDB0(1, 0);
        STAGE(Ab, 128, (u + 2) * 64, &ldsA[0][128 * 64]);
        BARRIER(); MM0(0, 0); BARRIER();
        // P6
        LDB1(1, 1);
        STAGE(Ab, 0, (u + 3) * 64, &ldsA[1][0]);
        BARRIER(); MM1(0, 1); BARRIER();
        // P7
        LDA(1, 1);
        STAGE(Bt, 0, (u + 3) * 64, &ldsB[1][0]);
        BARRIER(); MM1(1, 1); BARRIER();
        // P8
        STAGE(Bt, 128, (u + 3) * 64, &ldsB[1][128 * 64]);
        VMCNT6();          // all of buf0 (tile u+2) landed
        BARRIER(); MM0(1, 0); BARRIER();
    }

    // ---- epilogue: tiles 30 (buf0), 31 (buf1); only stage left: b1.Ahi(31) ----
    LDA(0, 0); LDB0(0, 0);
    STAGE(Ab, 128, 31 * 64, &ldsA[1][128 * 64]);
    BARRIER(); MM0(0, 0); BARRIER();
    LDB1(0, 1);
    BARRIER(); MM1(0, 1); BARRIER();
    LDA(0, 1);
    BARRIER(); MM1(1, 1); BARRIER();
    VMCNT0();
    BARRIER(); MM0(1, 0); BARRIER();
    LDA(1, 0); LDB0(1, 0);
    BARRIER(); MM0(0, 0); BARRIER();
    LDB1(1, 1);
    BARRIER(); MM1(0, 1); BARRIER();
    LDA(1, 1);
    BARRIER(); MM1(1, 1); BARRIER();
    MM0(1, 0);

    // ---- C write: row half from mf>>2, offset wfm within half ----
    #pragma unroll
    for (int mf = 0; mf < 8; ++mf) {
        #pragma unroll
        for (int r = 0; r < 4; ++r) {
            size_t row = (size_t)(m0 + (mf >> 2) * 128 + wfm + (mf & 3) * 16 + quad * 4 + r);
            #pragma unroll
            for (int nf = 0; nf < 4; ++nf) {
                int col = n0 + wfn + nf * 16 + idx;
                C[row * Nc + col] = f2b(acc[mf][nf][r]);
            }
        }
    }
}

// ---------- tiled GEMM: C[M,N] = A[M,K] * Bt[N,K]^T (wo projection, dbuf) ----------
__device__ __forceinline__ void g_stage(
    const unsigned short* __restrict__ A, const unsigned short* __restrict__ Bt,
    unsigned short* As, unsigned short* Bs,
    int k0, int K, int w, int srow, int schunk)
{
    #pragma unroll
    for (int i = 0; i < 4; ++i) {
        int cb = w * 4 + i;
        size_t goff = (size_t)(cb * 8 + srow) * K + k0 + schunk * 8;
        async_copy16(A  + goff, &As[cb * 512]);
        async_copy16(Bt + goff, &Bs[cb * 512]);
    }
}
__device__ __forceinline__ void g_compute(
    const unsigned short* As, const unsigned short* Bs,
    f32x4 (&acc)[4][4], int wm, int wn, int idx, int quad)
{
    #pragma unroll
    for (int ks = 0; ks < 2; ++ks) {
        bf16x8 af[4], bfr[4];
        #pragma unroll
        for (int mi = 0; mi < 4; ++mi) {
            int row = wm + mi * 16 + idx;
            af[mi] = *(const bf16x8*)&As[row * 64 + (((ks * 4 + quad) ^ (row & 7)) * 8)];
        }
        #pragma unroll
        for (int ni = 0; ni < 4; ++ni) {
            int row = wn + ni * 16 + idx;
            bfr[ni] = *(const bf16x8*)&Bs[row * 64 + (((ks * 4 + quad) ^ (row & 7)) * 8)];
        }
        #pragma unroll
        for (int mi = 0; mi < 4; ++mi)
            #pragma unroll
            for (int ni = 0; ni < 4; ++ni)
                acc[mi][ni] = MFMA16(af[mi], bfr[ni], acc[mi][ni]);
    }
}

template <typename OutT>
__global__ __launch_bounds__(256) void gemm_tile(
    const unsigned short* __restrict__ A,
    const unsigned short* __restrict__ Bt,
    OutT* __restrict__ C,
    int M, int N, int K)
{
    constexpr int BK = 64;
    __shared__ unsigned short As0[128 * BK];
    __shared__ unsigned short Bs0[128 * BK];
    __shared__ unsigned short As1[128 * BK];
    __shared__ unsigned short Bs1[128 * BK];

    int tid  = threadIdx.x;
    int w    = tid >> 6;
    int lane = tid & 63;
    int idx  = lane & 15;
    int quad = lane >> 4;
    int wm   = (w >> 1) * 64;
    int wn   = (w & 1) * 64;

    int tilesN = N / 128;
    int bm = blockIdx.x / tilesN;
    int bn = blockIdx.x - bm * tilesN;
    int m0 = bm * 128, n0 = bn * 128;

    const unsigned short* Ab = A  + (size_t)m0 * K;
    const unsigned short* Bb = Bt + (size_t)n0 * K;

    int srow   = lane >> 3;
    int schunk = (lane & 7) ^ srow;

    f32x4 acc[4][4];
    #pragma unroll
    for (int mi = 0; mi < 4; ++mi)
        #pragma unroll
        for (int ni = 0; ni < 4; ++ni) acc[mi][ni] = (f32x4){0.f, 0.f, 0.f, 0.f};

    g_stage(Ab, Bb, As0, Bs0, 0, K, w, srow, schunk);
    __syncthreads();

    for (int k0 = 0; k0 < K; k0 += 2 * BK) {
        if (k0 + BK < K)
            g_stage(Ab, Bb, As1, Bs1, k0 + BK, K, w, srow, schunk);
        g_compute(As0, Bs0, acc, wm, wn, idx, quad);
        __syncthreads();
        if (k0 + 2 * BK < K)
            g_stage(Ab, Bb, As0, Bs0, k0 + 2 * BK, K, w, srow, schunk);
        g_compute(As1, Bs1, acc, wm, wn, idx, quad);
        __syncthreads();
    }

    #pragma unroll
    for (int mi = 0; mi < 4; ++mi) {
        #pragma unroll
        for (int r = 0; r < 4; ++r) {
            size_t row = (size_t)(m0 + wm + mi * 16 + quad * 4 + r);
            #pragma unroll
            for (int ni = 0; ni < 4; ++ni) {
                int col = n0 + wn + ni * 16 + idx;
                if constexpr (std::is_same_v<OutT, float>) {
                    C[row * N + col] = acc[mi][ni][r];
                } else {
                    C[row * N + col] = f2b(acc[mi][ni][r]);
                }
            }
        }
    }
}

// ---------- RoPE (in-place on bf16, f32 freqs; oscale folds attn scale into q) ----------
__global__ __launch_bounds__(256) void rope_kernel(
    unsigned short* __restrict__ x,
    const float* __restrict__ cs,
    const float* __restrict__ sn,
    int H, int total, float oscale)
{
    int e = blockIdx.x * blockDim.x + threadIdx.x;
    if (e >= total) return;
    int i = e & 63;
    int s = (e / (64 * H)) & 2047;   // S = 2048
    float xr = b2f(x[2 * e]);
    float xi = b2f(x[2 * e + 1]);
    float c  = cs[s * 64 + i];
    float sv = sn[s * 64 + i];
    x[2 * e]     = f2b((xr * c - xi * sv) * oscale);
    x[2 * e + 1] = f2b((xr * sv + xi * c) * oscale);
}

// ---------- MFMA flash attention v6: 512 blocks x 512 threads ----------
// v5 + (a) T14 async-STAGE split with double-buffered Ks/Vt: issue tile t+1's
// K-DMA + V reg-loads BEFORE computing tile t; vmcnt(0) + Vt write + ONE
// barrier per iteration (was 2). Load latency hides under QK^T/softmax/PV.
// (b) pair-exchange V staging: lane-parity pairs load the two key-halves of
// one d-column pair, swap lo/hi halves via 2x shfl_xor(1), each thread does
// ONE ds_write_b128 at slot s^((row>>3)&3) -> 2-way (free) vs old 4-way on
// 2x ds_write_b64. Read side (quad^((rr>>3)&3)) unchanged: col c=s*8+ii <->
// key s*4+(ii>>1)+16*(ii&1) mapping preserved exactly.
__global__ __launch_bounds__(512, 4) void flash_attn(
    const unsigned short* __restrict__ qg,
    const unsigned short* __restrict__ kk,
    const unsigned short* __restrict__ vv,
    unsigned short* __restrict__ out)
{
    const int S = 2048;
    int bid = blockIdx.x;
    int qp  = bid & 15;
    int bh  = bid >> 4;            // b*16 + h
    int h   = bh & 15;
    int b   = bh >> 4;
    int kvh = h >> 2;

    int p   = b ? (15 - qp) : qp;  // co-resident blocks sum to 68 iters

    int tid  = threadIdx.x;
    int w    = tid >> 6;           // 0..7
    int lane = tid & 63;
    int idx  = lane & 15;
    int quad = lane >> 4;

    int qt  = 2 * p + (w >> 2);    // waves 0-3: tile 2p, waves 4-7: tile 2p+1
    int q0  = qt * 64;
    int wq0 = q0 + (w & 3) * 16;
    int qr  = wq0 + idx;

    __shared__ unsigned short Ks[2][32 * 128];   // XOR-chunk-swizzled rows
    __shared__ unsigned short Vt[2][128 * 40];   // V^T, key-permuted, slot-swizzled

    const unsigned short* kbase = kk + ((size_t)b * S * 4 + kvh) * 128;
    const unsigned short* vbase = vv + ((size_t)b * S * 4 + kvh) * 128;

    // Q fragments (B-operand): lane idx = qrow
    bf16x8 qf[4];
    {
        const unsigned short* qpp =
            qg + ((size_t)((b * S + wq0 + idx) * 16 + h)) * 128 + quad * 8;
        #pragma unroll
        for (int ko = 0; ko < 4; ++ko)
            qf[ko] = *(const bf16x8*)(qpp + ko * 32);
    }

    f32x4 acc[8];
    #pragma unroll
    for (int n = 0; n < 8; ++n) acc[n] = (f32x4){0.f, 0.f, 0.f, 0.f};
    float lsum = 0.f;

    // --- V staging geometry (pair-exchange b128) ---
    int s_   = w & 3;                 // slot / key-group 0..3
    int vr   = (w >> 2) * 64 + lane;  // Vt row this thread writes (0..127)
    int vodd = lane & 1;              // key-half: even->ii 0..3, odd->ii 4..7
    int cpb  = vr & ~1;               // d-column pair base
    int vwoff = vr * 40 + ((s_ ^ ((vr >> 3) & 3)) << 3);

    // --- K staging: wave w stages rows w*4..w*4+3 via DMA ---
    int key = w * 4 + (lane >> 4);
    int ksc = (lane & 15) ^ (key & 7);

    int nt = 4 * p + 4;               // heavy tile (2p+1) iteration count

    unsigned int vld[4];

    // issue stage of tile t into buf d: K DMA + 4 V u32 reg-loads
    auto STAGE_ISSUE = [&](int t, int d) {
        async_copy16(kbase + ((size_t)(t * 32 + key)) * 512 + ksc * 8,
                     &Ks[d][w * 512]);
        const unsigned short* vc = vbase + ((size_t)t * 32) * 512 + cpb;
        #pragma unroll
        for (int i = 0; i < 4; ++i) {
            int ii = vodd * 4 + i;
            int gk = s_ * 4 + (ii >> 1) + 16 * (ii & 1);
            vld[i] = *(const unsigned int*)(vc + (size_t)gk * 512);
        }
    };
    // finish V stage: pair-exchange + one b128 write into buf d
    auto STAGE_WRITE = [&](int d) {
        unsigned int L01 = (vld[0] & 0xffffu) | (vld[1] << 16);
        unsigned int L23 = (vld[2] & 0xffffu) | (vld[3] << 16);
        unsigned int H01 = (vld[0] >> 16) | (vld[1] & 0xffff0000u);
        unsigned int H23 = (vld[2] >> 16) | (vld[3] & 0xffff0000u);
        unsigned int x0 = vodd ? L01 : H01;   // even sends hi, odd sends lo
        unsigned int x1 = vodd ? L23 : H23;
        unsigned int y0 = __shfl_xor(x0, 1);
        unsigned int y1 = __shfl_xor(x1, 1);
        u32x4 row;
        if (vodd) row = (u32x4){y0, y1, H01, H23};   // odd row: hi of ii 0..7
        else      row = (u32x4){L01, L23, y0, y1};   // even row: lo of ii 0..7
        *(u32x4*)&Vt[d][vwoff] = row;
    };

    // ---- prologue: stage tile 0 into buf 0 ----
    STAGE_ISSUE(0, 0);
    VMCNT0();
    STAGE_WRITE(0);
    __syncthreads();

    // ---- main loop: 1 barrier / iteration ----
    for (int t = 0; t < nt; ++t) {
        int bc = t & 1;
        if (t + 1 < nt) STAGE_ISSUE(t + 1, bc ^ 1);

        if (t * 32 <= wq0 + 15) {   // tile within this wave's causal range
            // --- S^T = K·Q^T ---
            f32x4 s0 = {0.f,0.f,0.f,0.f}, s1 = {0.f,0.f,0.f,0.f};
            #pragma unroll
            for (int ko = 0; ko < 4; ++ko) {
                int kc = ko * 4 + quad;
                bf16x8 kf0 = *(const bf16x8*)&Ks[bc][idx * 128 + ((kc ^ (idx & 7)) * 8)];
                bf16x8 kf1 = *(const bf16x8*)&Ks[bc][(16 + idx) * 128 + ((kc ^ (idx & 7)) * 8)];
                s0 = MFMA16(kf0, qf[ko], s0);
                s1 = MFMA16(kf1, qf[ko], s1);
            }
            // --- mask + exp2 (no max); pk pairs = PV B-frag directly ---
            unsigned int pk[4];
            if (t * 32 + 31 <= wq0) {          // full tile (wave-uniform path)
                #pragma unroll
                for (int r = 0; r < 4; ++r) {
                    float p0 = EXP2F(s0[r]);
                    float p1 = EXP2F(s1[r]);
                    lsum += p0 + p1;
                    pk[r] = (unsigned int)f2b(p0) | ((unsigned int)f2b(p1) << 16);
                }
            } else {                            // diagonal tile
                int L = qr - t * 32;
                #pragma unroll
                for (int r = 0; r < 4; ++r) {
                    int kl = quad * 4 + r;
                    float p0 = (kl      <= L) ? EXP2F(s0[r]) : 0.f;
                    float p1 = (kl + 16 <= L) ? EXP2F(s1[r]) : 0.f;
                    lsum += p0 + p1;
                    pk[r] = (unsigned int)f2b(p0) | ((unsigned int)f2b(p1) << 16);
                }
            }
            u32x4 pku = {pk[0], pk[1], pk[2], pk[3]};
            bf16x8 pf = __builtin_bit_cast(bf16x8, pku);
            // --- PV: O^T += V^T · P^T ---
            #pragma unroll
            for (int n = 0; n < 8; ++n) {
                int rr = n * 16 + idx;
                bf16x8 vf = *(const bf16x8*)&Vt[bc][rr * 40 + ((quad ^ ((rr >> 3) & 3)) << 3)];
                acc[n] = MFMA16(vf, pf, acc[n]);
            }
        }

        if (t + 1 < nt) {
            VMCNT0();               // V regs + K DMA (issued pre-compute) landed
            STAGE_WRITE(bc ^ 1);
        }
        __syncthreads();            // tile t+1 ready; Vt[bc^1] writes visible
    }

    // --- epilogue ---
    lsum += __shfl_xor(lsum, 16);
    lsum += __shfl_xor(lsum, 32);
    float inv = 1.f / lsum;
    size_t rowb = (size_t)(b * S + wq0 + idx) * 2048 + h * 128;
    #pragma unroll
    for (int n = 0; n < 8; ++n) {
        ushort4 o;
        o.x = f2b(acc[n][0] * inv);
        o.y = f2b(acc[n][1] * inv);
        o.z = f2b(acc[n][2] * inv);
        o.w = f2b(acc[n][3] * inv);
        *(ushort4*)&out[rowb + n * 16 + quad * 4] = o;
    }
}

// ---------- launch ----------
extern "C" void kernel_launch(void* const* d_in, const int* in_sizes, int n_in,
                              void* d_out, int out_size, void* d_ws, size_t ws_size,
                              hipStream_t stream)
{
    const float* x  = (const float*)d_in[0];
    const float* fc = (const float*)d_in[1];
    const float* fs = (const float*)d_in[2];
    const float* wq = (const float*)d_in[3];
    const float* wk = (const float*)d_in[4];
    const float* wv = (const float*)d_in[5];
    const float* wo = (const float*)d_in[6];
    float* out = (float*)d_out;

    const int B = 2, S = 2048, D = 2048, KV = 512;
    const int M = B * S;                 // 4096

    unsigned short* ws  = (unsigned short*)d_ws;
    unsigned short* xb  = ws;                         // 4096*2048
    unsigned short* wqb = xb  + (size_t)M * D;        // 2048*2048
    unsigned short* wkb = wqb + (size_t)D * D;        // 512*2048
    unsigned short* wvb = wkb + (size_t)KV * D;       // 512*2048
    unsigned short* wob = wvb + (size_t)KV * D;       // 2048*2048
    unsigned short* qb  = wob + (size_t)D * D;        // 4096*2048
    unsigned short* kb  = qb  + (size_t)M * D;        // 4096*512
    unsigned short* vb  = kb  + (size_t)M * KV;       // 4096*512
    unsigned short* ao  = vb  + (size_t)M * KV;       // 4096*2048

    cvt_f32_to_bf16<<<dim3((M * D / 4) / 256), dim3(256), 0, stream>>>(x,  xb,  M * D / 4);
    cvt_f32_to_bf16<<<dim3((D * D / 4) / 256), dim3(256), 0, stream>>>(wq, wqb, D * D / 4);
    cvt_f32_to_bf16<<<dim3((KV * D / 4) / 256), dim3(256), 0, stream>>>(wk, wkb, KV * D / 4);
    cvt_f32_to_bf16<<<dim3((KV * D / 4) / 256), dim3(256), 0, stream>>>(wv, wvb, KV * D / 4);
    cvt_f32_to_bf16<<<dim3((D * D / 4) / 256), dim3(256), 0, stream>>>(wo, wob, D * D / 4);

    // fused QKV projection: 16 m-tiles x 12 n-tiles = 192 blocks, 512 thr
    qkv_gemm<<<dim3(192), dim3(512), 0, stream>>>(xb, wqb, wkb, wvb, qb, kb, vb);

    int qpairs = B * S * 16 * 64;
    int kpairs = B * S * 4 * 64;
    const float c2 = 0.12752584f;   // (1/sqrt(128)) * log2(e), folded into q
    rope_kernel<<<dim3(qpairs / 256), dim3(256), 0, stream>>>(qb, fc, fs, 16, qpairs, c2);
    rope_kernel<<<dim3(kpairs / 256), dim3(256), 0, stream>>>(kb, fc, fs, 4, kpairs, 1.0f);

    // flash attention: 512 blocks x 512 threads (8 waves, adjacent tile-pair)
    flash_attn<<<dim3(512), dim3(512), 0, stream>>>(qb, kb, vb, ao);

    gemm_tile<float><<<dim3((M / 128) * (D / 128)), dim3(256), 0, stream>>>(ao, wob, out, M, D, D);
}

// Round 8
// 315.947 us; speedup vs baseline: 1.0341x; 1.0052x over previous
//
#include <hip/hip_runtime.h>
#include <hip/hip_bf16.h>
#include <type_traits>

// ---------- types / helpers ----------
using bf16x8 = __attribute__((ext_vector_type(8))) short;   // 8 bf16 in 4 VGPRs
using f32x4  = __attribute__((ext_vector_type(4))) float;
using u16x8  = __attribute__((ext_vector_type(8))) unsigned short;
using u16x4  = __attribute__((ext_vector_type(4))) unsigned short;
using u32x4  = __attribute__((ext_vector_type(4))) unsigned int;

__device__ __forceinline__ float b2f(unsigned short u) {
    unsigned int x = ((unsigned int)u) << 16;
    return __builtin_bit_cast(float, x);
}
__device__ __forceinline__ unsigned short f2b(float f) {
    __hip_bfloat16 h = __float2bfloat16(f);   // RN
    return __builtin_bit_cast(unsigned short, h);
}

// exp2: bounded-domain scores, hardware v_exp_f32 either way
#if defined(__has_builtin)
#if __has_builtin(__builtin_amdgcn_exp2f)
#define EXP2F(x) __builtin_amdgcn_exp2f(x)
#else
#define EXP2F(x) exp2f(x)
#endif
#else
#define EXP2F(x) exp2f(x)
#endif

// async global->LDS, 16 B per lane; LDS dest is wave-uniform base + lane*16
__device__ __forceinline__ void async_copy16(const void* g, void* l) {
    __builtin_amdgcn_global_load_lds(
        (const __attribute__((address_space(1))) unsigned int*)g,
        (__attribute__((address_space(3))) unsigned int*)l, 16, 0, 0);
}

#define MFMA16(a, b, c) __builtin_amdgcn_mfma_f32_16x16x32_bf16(a, b, c, 0, 0, 0)

// raw barrier with compiler memory fence (no vmcnt/lgkmcnt drain)
#define BARRIER() do { asm volatile("" ::: "memory"); \
    __builtin_amdgcn_s_barrier(); asm volatile("" ::: "memory"); } while (0)
#define VMCNT6() asm volatile("s_waitcnt vmcnt(6)" ::: "memory")
#define VMCNT0() asm volatile("s_waitcnt vmcnt(0)" ::: "memory")

// ---------- f32 -> bf16 conversion (4 elems/thread) ----------
__global__ __launch_bounds__(256) void cvt_f32_to_bf16(
    const float* __restrict__ s, unsigned short* __restrict__ d, int n4)
{
    int i = blockIdx.x * blockDim.x + threadIdx.x;
    if (i >= n4) return;
    float4 v = ((const float4*)s)[i];
    ushort4 o;
    o.x = f2b(v.x); o.y = f2b(v.y); o.z = f2b(v.z); o.w = f2b(v.w);
    ((ushort4*)d)[i] = o;
}

// ---------- fused QKV GEMM, 256x256 8-phase template (T3+T4+T5) ----------
// [Q|K|V] = x @ [wq;wk;wv]^T.  M=4096, Ntot=3072, K=2048.
// Grid 16m x 12n = 192 blocks, 512 threads (8 waves), BK=64.
// LDS 128KB: 2 dbuf x (A,B) x 256x64 bf16, staged in 128-row halves.
// Wave m: wfm=(w>>2)*64; wave's m-halves are {wfm..} (A-low, read P1) and
// {128+wfm..} (A-high, read P3) -- read half matches stage half.
// 8 phases per 2 K-tiles; vmcnt(6) ONLY at P4/P8 (3 half-tiles in flight).
__global__ __launch_bounds__(512, 2) void qkv_gemm(
    const unsigned short* __restrict__ A,    // M x 2048
    const unsigned short* __restrict__ Wq,   // 2048 x 2048
    const unsigned short* __restrict__ Wk,   // 512 x 2048
    const unsigned short* __restrict__ Wv,   // 512 x 2048
    unsigned short* __restrict__ Q,          // M x 2048
    unsigned short* __restrict__ Kk,         // M x 512
    unsigned short* __restrict__ V)          // M x 512
{
    const int K = 2048;
    __shared__ unsigned short ldsA[2][256 * 64];
    __shared__ unsigned short ldsB[2][256 * 64];

    int tid  = threadIdx.x;
    int w    = tid >> 6;           // 0..7
    int lane = tid & 63;
    int idx  = lane & 15;
    int quad = lane >> 4;
    int srow   = lane >> 3;
    int schunk = (lane & 7) ^ srow;

    int wfm = (w >> 2) * 64;       // wave m-offset within each 128-row half
    int wfn = (w & 3) * 64;        // wave n-offset

    // XCD-contiguous swizzle (192 % 8 == 0, bijective)
    int bid = (blockIdx.x & 7) * 24 + (blockIdx.x >> 3);
    int bm = bid / 12;
    int bn = bid - bm * 12;
    int m0 = bm * 256;

    const unsigned short* Bt;
    unsigned short* C;
    int Nc, n0;
    if (bn < 8)       { Bt = Wq + (size_t)bn * 256 * K;        C = Q;  Nc = 2048; n0 = bn * 256; }
    else if (bn < 10) { Bt = Wk + (size_t)(bn - 8) * 256 * K;  C = Kk; Nc = 512;  n0 = (bn - 8) * 256; }
    else              { Bt = Wv + (size_t)(bn - 10) * 256 * K; C = V;  Nc = 512;  n0 = (bn - 10) * 256; }

    const unsigned short* Ab = A + (size_t)m0 * K;

    f32x4 acc[8][4];
    #pragma unroll
    for (int mf = 0; mf < 8; ++mf)
        #pragma unroll
        for (int nf = 0; nf < 4; ++nf) acc[mf][nf] = (f32x4){0.f, 0.f, 0.f, 0.f};

    bf16x8 a[4][2], b0[2][2], b1[2][2];

    // stage one 128x64 half-tile (2 global_load_lds / thread)
    auto STAGE = [&](const unsigned short* __restrict__ G, int rb, int kc,
                     unsigned short* dst) {
        #pragma unroll
        for (int i = 0; i < 2; ++i) {
            int R = (w * 2 + i) * 8;
            async_copy16(G + (size_t)(rb + R + srow) * K + kc + schunk * 8,
                         dst + (size_t)R * 64);
        }
    };
    // mh selects the 128-row staging half; wave reads rows mh*128+wfm+...
    auto LDA = [&](int d, int mh) {
        #pragma unroll
        for (int mi = 0; mi < 4; ++mi) {
            int r = mh * 128 + wfm + mi * 16 + idx;
            #pragma unroll
            for (int ks = 0; ks < 2; ++ks)
                a[mi][ks] = *(const bf16x8*)&ldsA[d][r * 64 + (((ks * 4 + quad) ^ (r & 7)) << 3)];
        }
    };
    auto LDB0 = [&](int d, int nh) {
        #pragma unroll
        for (int nj = 0; nj < 2; ++nj) {
            int r = wfn + nh * 32 + nj * 16 + idx;
            #pragma unroll
            for (int ks = 0; ks < 2; ++ks)
                b0[nj][ks] = *(const bf16x8*)&ldsB[d][r * 64 + (((ks * 4 + quad) ^ (r & 7)) << 3)];
        }
    };
    auto LDB1 = [&](int d, int nh) {
        #pragma unroll
        for (int nj = 0; nj < 2; ++nj) {
            int r = wfn + nh * 32 + nj * 16 + idx;
            #pragma unroll
            for (int ks = 0; ks < 2; ++ks)
                b1[nj][ks] = *(const bf16x8*)&ldsB[d][r * 64 + (((ks * 4 + quad) ^ (r & 7)) << 3)];
        }
    };
    auto MM0 = [&](int mh, int nh) {   // quadrant with b0
        __builtin_amdgcn_s_setprio(1);
        #pragma unroll
        for (int mi = 0; mi < 4; ++mi)
            #pragma unroll
            for (int nj = 0; nj < 2; ++nj)
                #pragma unroll
                for (int ks = 0; ks < 2; ++ks)
                    acc[mh * 4 + mi][nh * 2 + nj] =
                        MFMA16(a[mi][ks], b0[nj][ks], acc[mh * 4 + mi][nh * 2 + nj]);
        __builtin_amdgcn_s_setprio(0);
    };
    auto MM1 = [&](int mh, int nh) {   // quadrant with b1
        __builtin_amdgcn_s_setprio(1);
        #pragma unroll
        for (int mi = 0; mi < 4; ++mi)
            #pragma unroll
            for (int nj = 0; nj < 2; ++nj)
                #pragma unroll
                for (int ks = 0; ks < 2; ++ks)
                    acc[mh * 4 + mi][nh * 2 + nj] =
                        MFMA16(a[mi][ks], b1[nj][ks], acc[mh * 4 + mi][nh * 2 + nj]);
        __builtin_amdgcn_s_setprio(0);
    };

    // ---- prologue: tile0 full into buf0, tile1 Alo/Blo/Bhi into buf1 ----
    STAGE(Ab, 0,   0,  &ldsA[0][0]);
    STAGE(Ab, 128, 0,  &ldsA[0][128 * 64]);
    STAGE(Bt, 0,   0,  &ldsB[0][0]);
    STAGE(Bt, 128, 0,  &ldsB[0][128 * 64]);
    STAGE(Ab, 0,   64, &ldsA[1][0]);
    STAGE(Bt, 0,   64, &ldsB[1][0]);
    STAGE(Bt, 128, 64, &ldsB[1][128 * 64]);
    VMCNT6();          // tile0 (8 oldest loads) landed; 6 outstanding
    BARRIER();

    // ---- main loop: 15 iters, tiles u=2it, u+1; stages u+2, u+3 (max 31) ----
    for (int it = 0; it < 15; ++it) {
        int u = 2 * it;
        // P1
        LDA(0, 0); LDB0(0, 0);
        STAGE(Ab, 128, (u + 1) * 64, &ldsA[1][128 * 64]);
        BARRIER(); MM0(0, 0); BARRIER();
        // P2
        LDB1(0, 1);
        STAGE(Ab, 0, (u + 2) * 64, &ldsA[0][0]);
        BARRIER(); MM1(0, 1); BARRIER();
        // P3
        LDA(0, 1);
        STAGE(Bt, 0, (u + 2) * 64, &ldsB[0][0]);
        BARRIER(); MM1(1, 1); BARRIER();
        // P4
        STAGE(Bt, 128, (u + 2) * 64, &ldsB[0][128 * 64]);
        VMCNT6();          // all of buf1 (tile u+1) landed
        BARRIER(); MM0(1, 0); BARRIER();
        // P5
        LDA(1, 0); LDB0(1, 0);
        STAGE(Ab, 128, (u + 2) * 64, &ldsA[0][128 * 64]);
        BARRIER(); MM0(0, 0); BARRIER();
        // P6
        LDB1(1, 1);
        STAGE(Ab, 0, (u + 3) * 64, &ldsA[1][0]);
        BARRIER(); MM1(0, 1); BARRIER();
        // P7
        LDA(1, 1);
        STAGE(Bt, 0, (u + 3) * 64, &ldsB[1][0]);
        BARRIER(); MM1(1, 1); BARRIER();
        // P8
        STAGE(Bt, 128, (u + 3) * 64, &ldsB[1][128 * 64]);
        VMCNT6();          // all of buf0 (tile u+2) landed
        BARRIER(); MM0(1, 0); BARRIER();
    }

    // ---- epilogue: tiles 30 (buf0), 31 (buf1); only stage left: b1.Ahi(31) ----
    LDA(0, 0); LDB0(0, 0);
    STAGE(Ab, 128, 31 * 64, &ldsA[1][128 * 64]);
    BARRIER(); MM0(0, 0); BARRIER();
    LDB1(0, 1);
    BARRIER(); MM1(0, 1); BARRIER();
    LDA(0, 1);
    BARRIER(); MM1(1, 1); BARRIER();
    VMCNT0();
    BARRIER(); MM0(1, 0); BARRIER();
    LDA(1, 0); LDB0(1, 0);
    BARRIER(); MM0(0, 0); BARRIER();
    LDB1(1, 1);
    BARRIER(); MM1(0, 1); BARRIER();
    LDA(1, 1);
    BARRIER(); MM1(1, 1); BARRIER();
    MM0(1, 0);

    // ---- C write: row half from mf>>2, offset wfm within half ----
    #pragma unroll
    for (int mf = 0; mf < 8; ++mf) {
        #pragma unroll
        for (int r = 0; r < 4; ++r) {
            size_t row = (size_t)(m0 + (mf >> 2) * 128 + wfm + (mf & 3) * 16 + quad * 4 + r);
            #pragma unroll
            for (int nf = 0; nf < 4; ++nf) {
                int col = n0 + wfn + nf * 16 + idx;
                C[row * Nc + col] = f2b(acc[mf][nf][r]);
            }
        }
    }
}

// ---------- tiled GEMM: C[M,N] = A[M,K] * Bt[N,K]^T (wo projection, dbuf) ----------
__device__ __forceinline__ void g_stage(
    const unsigned short* __restrict__ A, const unsigned short* __restrict__ Bt,
    unsigned short* As, unsigned short* Bs,
    int k0, int K, int w, int srow, int schunk)
{
    #pragma unroll
    for (int i = 0; i < 4; ++i) {
        int cb = w * 4 + i;
        size_t goff = (size_t)(cb * 8 + srow) * K + k0 + schunk * 8;
        async_copy16(A  + goff, &As[cb * 512]);
        async_copy16(Bt + goff, &Bs[cb * 512]);
    }
}
__device__ __forceinline__ void g_compute(
    const unsigned short* As, const unsigned short* Bs,
    f32x4 (&acc)[4][4], int wm, int wn, int idx, int quad)
{
    #pragma unroll
    for (int ks = 0; ks < 2; ++ks) {
        bf16x8 af[4], bfr[4];
        #pragma unroll
        for (int mi = 0; mi < 4; ++mi) {
            int row = wm + mi * 16 + idx;
            af[mi] = *(const bf16x8*)&As[row * 64 + (((ks * 4 + quad) ^ (row & 7)) * 8)];
        }
        #pragma unroll
        for (int ni = 0; ni < 4; ++ni) {
            int row = wn + ni * 16 + idx;
            bfr[ni] = *(const bf16x8*)&Bs[row * 64 + (((ks * 4 + quad) ^ (row & 7)) * 8)];
        }
        #pragma unroll
        for (int mi = 0; mi < 4; ++mi)
            #pragma unroll
            for (int ni = 0; ni < 4; ++ni)
                acc[mi][ni] = MFMA16(af[mi], bfr[ni], acc[mi][ni]);
    }
}

template <typename OutT>
__global__ __launch_bounds__(256) void gemm_tile(
    const unsigned short* __restrict__ A,
    const unsigned short* __restrict__ Bt,
    OutT* __restrict__ C,
    int M, int N, int K)
{
    constexpr int BK = 64;
    __shared__ unsigned short As0[128 * BK];
    __shared__ unsigned short Bs0[128 * BK];
    __shared__ unsigned short As1[128 * BK];
    __shared__ unsigned short Bs1[128 * BK];

    int tid  = threadIdx.x;
    int w    = tid >> 6;
    int lane = tid & 63;
    int idx  = lane & 15;
    int quad = lane >> 4;
    int wm   = (w >> 1) * 64;
    int wn   = (w & 1) * 64;

    int tilesN = N / 128;
    int bm = blockIdx.x / tilesN;
    int bn = blockIdx.x - bm * tilesN;
    int m0 = bm * 128, n0 = bn * 128;

    const unsigned short* Ab = A  + (size_t)m0 * K;
    const unsigned short* Bb = Bt + (size_t)n0 * K;

    int srow   = lane >> 3;
    int schunk = (lane & 7) ^ srow;

    f32x4 acc[4][4];
    #pragma unroll
    for (int mi = 0; mi < 4; ++mi)
        #pragma unroll
        for (int ni = 0; ni < 4; ++ni) acc[mi][ni] = (f32x4){0.f, 0.f, 0.f, 0.f};

    g_stage(Ab, Bb, As0, Bs0, 0, K, w, srow, schunk);
    __syncthreads();

    for (int k0 = 0; k0 < K; k0 += 2 * BK) {
        if (k0 + BK < K)
            g_stage(Ab, Bb, As1, Bs1, k0 + BK, K, w, srow, schunk);
        g_compute(As0, Bs0, acc, wm, wn, idx, quad);
        __syncthreads();
        if (k0 + 2 * BK < K)
            g_stage(Ab, Bb, As0, Bs0, k0 + 2 * BK, K, w, srow, schunk);
        g_compute(As1, Bs1, acc, wm, wn, idx, quad);
        __syncthreads();
    }

    #pragma unroll
    for (int mi = 0; mi < 4; ++mi) {
        #pragma unroll
        for (int r = 0; r < 4; ++r) {
            size_t row = (size_t)(m0 + wm + mi * 16 + quad * 4 + r);
            #pragma unroll
            for (int ni = 0; ni < 4; ++ni) {
                int col = n0 + wn + ni * 16 + idx;
                if constexpr (std::is_same_v<OutT, float>) {
                    C[row * N + col] = acc[mi][ni][r];
                } else {
                    C[row * N + col] = f2b(acc[mi][ni][r]);
                }
            }
        }
    }
}

// ---------- RoPE (in-place on bf16, f32 freqs; oscale folds attn scale into q) ----------
__global__ __launch_bounds__(256) void rope_kernel(
    unsigned short* __restrict__ x,
    const float* __restrict__ cs,
    const float* __restrict__ sn,
    int H, int total, float oscale)
{
    int e = blockIdx.x * blockDim.x + threadIdx.x;
    if (e >= total) return;
    int i = e & 63;
    int s = (e / (64 * H)) & 2047;   // S = 2048
    float xr = b2f(x[2 * e]);
    float xi = b2f(x[2 * e + 1]);
    float c  = cs[s * 64 + i];
    float sv = sn[s * 64 + i];
    x[2 * e]     = f2b((xr * c - xi * sv) * oscale);
    x[2 * e + 1] = f2b((xr * sv + xi * c) * oscale);
}

// ---------- MFMA flash attention v7: 512 blocks x 256 threads ----------
// LDS-throughput fix: 32 q-rows per wave (two 16-row groups A/B) so each
// K/V fragment LDS read feeds TWO MFMAs -> LDS read bytes per unit work
// HALVED (R7 post-mortem: 16 waves x 16 KB/iter = 58 us pure-LDS floor was
// the bottleneck; MfmaUtil 16%, nothing else saturated). 4 waves x 64 lanes;
// wave w: tile 2p+(w>>1), rows wq0=qt*64+(w&1)*32 .. +31.
// V staging: 256 threads each own ALL 8 key-halves of a row pair ->
// two full ds_write_b128 slots, NO shuffles (v6's shfl_xor = ds_bpermute
// added traffic to the saturated LDS pipe - that was the v6 regression).
// Phase-exact bank check: writes conflict-free (8 lanes/phase -> 8 distinct
// 4-bank groups). Keeps v6's 1-barrier dbuf issue-early prefetch.
__global__ __launch_bounds__(256, 2) void flash_attn(
    const unsigned short* __restrict__ qg,
    const unsigned short* __restrict__ kk,
    const unsigned short* __restrict__ vv,
    unsigned short* __restrict__ out)
{
    const int S = 2048;
    int bid = blockIdx.x;
    int qp  = bid & 15;
    int bh  = bid >> 4;            // b*16 + h
    int h   = bh & 15;
    int b   = bh >> 4;
    int kvh = h >> 2;

    int p   = b ? (15 - qp) : qp;  // co-resident blocks sum to 68 iters

    int tid  = threadIdx.x;
    int w    = tid >> 6;           // 0..3
    int lane = tid & 63;
    int idx  = lane & 15;
    int quad = lane >> 4;

    int qt  = 2 * p + (w >> 1);    // waves 0-1: tile 2p, waves 2-3: tile 2p+1
    int wq0 = qt * 64 + (w & 1) * 32;   // wave owns rows wq0..wq0+31
    int qrA = wq0 + idx;                 // group A row; group B = +16

    __shared__ unsigned short Ks[2][32 * 128];   // XOR-chunk-swizzled rows
    __shared__ unsigned short Vt[2][128 * 40];   // V^T, key-permuted, slot-swizzled

    const unsigned short* kbase = kk + ((size_t)b * S * 4 + kvh) * 128;
    const unsigned short* vbase = vv + ((size_t)b * S * 4 + kvh) * 128;

    // Q fragments for both groups (B-operand): lane idx = qrow
    bf16x8 qfA[4], qfB[4];
    {
        const unsigned short* qa =
            qg + ((size_t)((b * S + wq0 + idx) * 16 + h)) * 128 + quad * 8;
        const unsigned short* qb2 =
            qg + ((size_t)((b * S + wq0 + 16 + idx) * 16 + h)) * 128 + quad * 8;
        #pragma unroll
        for (int ko = 0; ko < 4; ++ko) {
            qfA[ko] = *(const bf16x8*)(qa  + ko * 32);
            qfB[ko] = *(const bf16x8*)(qb2 + ko * 32);
        }
    }

    f32x4 accA[8], accB[8];
    #pragma unroll
    for (int n = 0; n < 8; ++n) {
        accA[n] = (f32x4){0.f, 0.f, 0.f, 0.f};
        accB[n] = (f32x4){0.f, 0.f, 0.f, 0.f};
    }
    float lsumA = 0.f, lsumB = 0.f;

    // --- K staging: wave w stages rows w*8..w*8+7 via 2 DMAs ---
    int key0 = w * 8 + (lane >> 4);
    int ksc0 = (lane & 15) ^ (key0 & 7);
    int ksc1 = (lane & 15) ^ ((key0 + 4) & 7);

    // --- V staging: thread owns row pair (dp, dp+1), col-slot s_=w ---
    // col c = w*8+ii maps to key kappa = w*4 + (ii>>1) + 16*(ii&1)
    int dp = lane * 2;
    int swzslot = ((w ^ ((dp >> 3) & 3)) << 3);   // shorts; dp,dp+1 same block

    int nt = 4 * p + 4;            // heavy tile (2p+1) iteration count

    unsigned int vld[8];

    auto STAGE_ISSUE = [&](int t, int d) {
        async_copy16(kbase + ((size_t)(t * 32 + key0)) * 512 + ksc0 * 8,
                     &Ks[d][(w * 8) * 128]);
        async_copy16(kbase + ((size_t)(t * 32 + key0 + 4)) * 512 + ksc1 * 8,
                     &Ks[d][(w * 8 + 4) * 128]);
        const unsigned short* vc = vbase + ((size_t)(t * 32 + w * 4)) * 512 + dp;
        #pragma unroll
        for (int ii = 0; ii < 8; ++ii) {
            int gk = (ii >> 1) + 16 * (ii & 1);
            vld[ii] = *(const unsigned int*)(vc + (size_t)gk * 512);
        }
    };
    auto STAGE_WRITE = [&](int d) {
        u16x8 lo, hi;
        #pragma unroll
        for (int ii = 0; ii < 8; ++ii) {
            lo[ii] = (unsigned short)vld[ii];
            hi[ii] = (unsigned short)(vld[ii] >> 16);
        }
        *(u16x8*)&Vt[d][dp * 40 + swzslot]       = lo;
        *(u16x8*)&Vt[d][(dp + 1) * 40 + swzslot] = hi;
    };

    // ---- prologue: stage tile 0 into buf 0 ----
    STAGE_ISSUE(0, 0);
    VMCNT0();
    STAGE_WRITE(0);
    __syncthreads();

    // ---- main loop: 1 barrier / iteration ----
    for (int t = 0; t < nt; ++t) {
        int bc = t & 1;
        if (t + 1 < nt) STAGE_ISSUE(t + 1, bc ^ 1);

        if (t * 32 <= wq0 + 31) {   // tile within this wave's causal range
            // --- S^T = K·Q^T for both q-groups (K frags read ONCE) ---
            f32x4 s0A = {0.f,0.f,0.f,0.f}, s1A = {0.f,0.f,0.f,0.f};
            f32x4 s0B = {0.f,0.f,0.f,0.f}, s1B = {0.f,0.f,0.f,0.f};
            #pragma unroll
            for (int ko = 0; ko < 4; ++ko) {
                int kc = ko * 4 + quad;
                bf16x8 kf0 = *(const bf16x8*)&Ks[bc][idx * 128 + ((kc ^ (idx & 7)) * 8)];
                bf16x8 kf1 = *(const bf16x8*)&Ks[bc][(16 + idx) * 128 + ((kc ^ (idx & 7)) * 8)];
                s0A = MFMA16(kf0, qfA[ko], s0A);
                s1A = MFMA16(kf1, qfA[ko], s1A);
                s0B = MFMA16(kf0, qfB[ko], s0B);
                s1B = MFMA16(kf1, qfB[ko], s1B);
            }
            // --- mask + exp2 (no max); pk pairs = PV B-frag directly ---
            unsigned int pkA[4], pkB[4];
            if (t * 32 + 31 <= wq0) {          // full tile for both groups
                #pragma unroll
                for (int r = 0; r < 4; ++r) {
                    float a0 = EXP2F(s0A[r]), a1 = EXP2F(s1A[r]);
                    float b0_ = EXP2F(s0B[r]), b1_ = EXP2F(s1B[r]);
                    lsumA += a0 + a1;
                    lsumB += b0_ + b1_;
                    pkA[r] = (unsigned int)f2b(a0) | ((unsigned int)f2b(a1) << 16);
                    pkB[r] = (unsigned int)f2b(b0_) | ((unsigned int)f2b(b1_) << 16);
                }
            } else {                            // diagonal tile
                int LA = qrA - t * 32;
                int LB = LA + 16;
                #pragma unroll
                for (int r = 0; r < 4; ++r) {
                    int kl = quad * 4 + r;
                    float a0 = (kl      <= LA) ? EXP2F(s0A[r]) : 0.f;
                    float a1 = (kl + 16 <= LA) ? EXP2F(s1A[r]) : 0.f;
                    float b0_ = (kl      <= LB) ? EXP2F(s0B[r]) : 0.f;
                    float b1_ = (kl + 16 <= LB) ? EXP2F(s1B[r]) : 0.f;
                    lsumA += a0 + a1;
                    lsumB += b0_ + b1_;
                    pkA[r] = (unsigned int)f2b(a0) | ((unsigned int)f2b(a1) << 16);
                    pkB[r] = (unsigned int)f2b(b0_) | ((unsigned int)f2b(b1_) << 16);
                }
            }
            u32x4 pkuA = {pkA[0], pkA[1], pkA[2], pkA[3]};
            u32x4 pkuB = {pkB[0], pkB[1], pkB[2], pkB[3]};
            bf16x8 pfA = __builtin_bit_cast(bf16x8, pkuA);
            bf16x8 pfB = __builtin_bit_cast(bf16x8, pkuB);
            // --- PV: O^T += V^T · P^T (V frags read ONCE, feed both groups) ---
            #pragma unroll
            for (int n = 0; n < 8; ++n) {
                int rr = n * 16 + idx;
                bf16x8 vf = *(const bf16x8*)&Vt[bc][rr * 40 + ((quad ^ ((rr >> 3) & 3)) << 3)];
                accA[n] = MFMA16(vf, pfA, accA[n]);
                accB[n] = MFMA16(vf, pfB, accB[n]);
            }
        }

        if (t + 1 < nt) {
            VMCNT0();               // V regs + K DMA (issued pre-compute) landed
            STAGE_WRITE(bc ^ 1);
        }
        __syncthreads();            // tile t+1 ready; buf writes visible
    }

    // --- epilogue ---
    lsumA += __shfl_xor(lsumA, 16);
    lsumA += __shfl_xor(lsumA, 32);
    lsumB += __shfl_xor(lsumB, 16);
    lsumB += __shfl_xor(lsumB, 32);
    float invA = 1.f / lsumA;
    float invB = 1.f / lsumB;
    size_t rowA = (size_t)(b * S + wq0 + idx) * 2048 + h * 128;
    size_t rowB = rowA + (size_t)16 * 2048;
    #pragma unroll
    for (int n = 0; n < 8; ++n) {
        ushort4 oA, oB;
        oA.x = f2b(accA[n][0] * invA);
        oA.y = f2b(accA[n][1] * invA);
        oA.z = f2b(accA[n][2] * invA);
        oA.w = f2b(accA[n][3] * invA);
        oB.x = f2b(accB[n][0] * invB);
        oB.y = f2b(accB[n][1] * invB);
        oB.z = f2b(accB[n][2] * invB);
        oB.w = f2b(accB[n][3] * invB);
        *(ushort4*)&out[rowA + n * 16 + quad * 4] = oA;
        *(ushort4*)&out[rowB + n * 16 + quad * 4] = oB;
    }
}

// ---------- launch ----------
extern "C" void kernel_launch(void* const* d_in, const int* in_sizes, int n_in,
                              void* d_out, int out_size, void* d_ws, size_t ws_size,
                              hipStream_t stream)
{
    const float* x  = (const float*)d_in[0];
    const float* fc = (const float*)d_in[1];
    const float* fs = (const float*)d_in[2];
    const float* wq = (const float*)d_in[3];
    const float* wk = (const float*)d_in[4];
    const float* wv = (const float*)d_in[5];
    const float* wo = (const float*)d_in[6];
    float* out = (float*)d_out;

    const int B = 2, S = 2048, D = 2048, KV = 512;
    const int M = B * S;                 // 4096

    unsigned short* ws  = (unsigned short*)d_ws;
    unsigned short* xb  = ws;                         // 4096*2048
    unsigned short* wqb = xb  + (size_t)M * D;        // 2048*2048
    unsigned short* wkb = wqb + (size_t)D * D;        // 512*2048
    unsigned short* wvb = wkb + (size_t)KV * D;       // 512*2048
    unsigned short* wob = wvb + (size_t)KV * D;       // 2048*2048
    unsigned short* qb  = wob + (size_t)D * D;        // 4096*2048
    unsigned short* kb  = qb  + (size_t)M * D;        // 4096*512
    unsigned short* vb  = kb  + (size_t)M * KV;       // 4096*512
    unsigned short* ao  = vb  + (size_t)M * KV;       // 4096*2048

    cvt_f32_to_bf16<<<dim3((M * D / 4) / 256), dim3(256), 0, stream>>>(x,  xb,  M * D / 4);
    cvt_f32_to_bf16<<<dim3((D * D / 4) / 256), dim3(256), 0, stream>>>(wq, wqb, D * D / 4);
    cvt_f32_to_bf16<<<dim3((KV * D / 4) / 256), dim3(256), 0, stream>>>(wk, wkb, KV * D / 4);
    cvt_f32_to_bf16<<<dim3((KV * D / 4) / 256), dim3(256), 0, stream>>>(wv, wvb, KV * D / 4);
    cvt_f32_to_bf16<<<dim3((D * D / 4) / 256), dim3(256), 0, stream>>>(wo, wob, D * D / 4);

    // fused QKV projection: 16 m-tiles x 12 n-tiles = 192 blocks, 512 thr
    qkv_gemm<<<dim3(192), dim3(512), 0, stream>>>(xb, wqb, wkb, wvb, qb, kb, vb);

    int qpairs = B * S * 16 * 64;
    int kpairs = B * S * 4 * 64;
    const float c2 = 0.12752584f;   // (1/sqrt(128)) * log2(e), folded into q
    rope_kernel<<<dim3(qpairs / 256), dim3(256), 0, stream>>>(qb, fc, fs, 16, qpairs, c2);
    rope_kernel<<<dim3(kpairs / 256), dim3(256), 0, stream>>>(kb, fc, fs, 4, kpairs, 1.0f);

    // flash attention: 512 blocks x 256 threads (4 waves, 32 q-rows/wave)
    flash_attn<<<dim3(512), dim3(256), 0, stream>>>(qb, kb, vb, ao);

    gemm_tile<float><<<dim3((M / 128) * (D / 128)), dim3(256), 0, stream>>>(ao, wob, out, M, D, D);
}

// Round 9
// 312.889 us; speedup vs baseline: 1.0442x; 1.0098x over previous
//
#include <hip/hip_runtime.h>
#include <hip/hip_bf16.h>
#include <type_traits>

// ---------- types / helpers ----------
using bf16x8 = __attribute__((ext_vector_type(8))) short;   // 8 bf16 in 4 VGPRs
using f32x4  = __attribute__((ext_vector_type(4))) float;
using u16x8  = __attribute__((ext_vector_type(8))) unsigned short;
using u16x4  = __attribute__((ext_vector_type(4))) unsigned short;
using u32x4  = __attribute__((ext_vector_type(4))) unsigned int;

__device__ __forceinline__ float b2f(unsigned short u) {
    unsigned int x = ((unsigned int)u) << 16;
    return __builtin_bit_cast(float, x);
}
__device__ __forceinline__ unsigned short f2b(float f) {
    __hip_bfloat16 h = __float2bfloat16(f);   // RN
    return __builtin_bit_cast(unsigned short, h);
}

// exp2: bounded-domain scores, hardware v_exp_f32 either way
#if defined(__has_builtin)
#if __has_builtin(__builtin_amdgcn_exp2f)
#define EXP2F(x) __builtin_amdgcn_exp2f(x)
#else
#define EXP2F(x) exp2f(x)
#endif
#else
#define EXP2F(x) exp2f(x)
#endif

// async global->LDS, 16 B per lane; LDS dest is wave-uniform base + lane*16
__device__ __forceinline__ void async_copy16(const void* g, void* l) {
    __builtin_amdgcn_global_load_lds(
        (const __attribute__((address_space(1))) unsigned int*)g,
        (__attribute__((address_space(3))) unsigned int*)l, 16, 0, 0);
}

#define MFMA16(a, b, c) __builtin_amdgcn_mfma_f32_16x16x32_bf16(a, b, c, 0, 0, 0)

// raw barrier with compiler memory fence (no vmcnt/lgkmcnt drain)
#define BARRIER() do { asm volatile("" ::: "memory"); \
    __builtin_amdgcn_s_barrier(); asm volatile("" ::: "memory"); } while (0)
#define VMCNT6() asm volatile("s_waitcnt vmcnt(6)" ::: "memory")
#define VMCNT0() asm volatile("s_waitcnt vmcnt(0)" ::: "memory")

// ---------- f32 -> bf16 conversion (4 elems/thread) ----------
__global__ __launch_bounds__(256) void cvt_f32_to_bf16(
    const float* __restrict__ s, unsigned short* __restrict__ d, int n4)
{
    int i = blockIdx.x * blockDim.x + threadIdx.x;
    if (i >= n4) return;
    float4 v = ((const float4*)s)[i];
    ushort4 o;
    o.x = f2b(v.x); o.y = f2b(v.y); o.z = f2b(v.z); o.w = f2b(v.w);
    ((ushort4*)d)[i] = o;
}

// ---------- fused QKV GEMM, 256x256 8-phase template (T3+T4+T5) ----------
// [Q|K|V] = x @ [wq;wk;wv]^T.  M=4096, Ntot=3072, K=2048.
// Grid 16m x 12n = 192 blocks, 512 threads (8 waves), BK=64.
// LDS 128KB: 2 dbuf x (A,B) x 256x64 bf16, staged in 128-row halves.
// Wave m: wfm=(w>>2)*64; wave's m-halves are {wfm..} (A-low, read P1) and
// {128+wfm..} (A-high, read P3) -- read half matches stage half.
// 8 phases per 2 K-tiles; vmcnt(6) ONLY at P4/P8 (3 half-tiles in flight).
__global__ __launch_bounds__(512, 2) void qkv_gemm(
    const unsigned short* __restrict__ A,    // M x 2048
    const unsigned short* __restrict__ Wq,   // 2048 x 2048
    const unsigned short* __restrict__ Wk,   // 512 x 2048
    const unsigned short* __restrict__ Wv,   // 512 x 2048
    unsigned short* __restrict__ Q,          // M x 2048
    unsigned short* __restrict__ Kk,         // M x 512
    unsigned short* __restrict__ V)          // M x 512
{
    const int K = 2048;
    __shared__ unsigned short ldsA[2][256 * 64];
    __shared__ unsigned short ldsB[2][256 * 64];

    int tid  = threadIdx.x;
    int w    = tid >> 6;           // 0..7
    int lane = tid & 63;
    int idx  = lane & 15;
    int quad = lane >> 4;
    int srow   = lane >> 3;
    int schunk = (lane & 7) ^ srow;

    int wfm = (w >> 2) * 64;       // wave m-offset within each 128-row half
    int wfn = (w & 3) * 64;        // wave n-offset

    // XCD-contiguous swizzle (192 % 8 == 0, bijective)
    int bid = (blockIdx.x & 7) * 24 + (blockIdx.x >> 3);
    int bm = bid / 12;
    int bn = bid - bm * 12;
    int m0 = bm * 256;

    const unsigned short* Bt;
    unsigned short* C;
    int Nc, n0;
    if (bn < 8)       { Bt = Wq + (size_t)bn * 256 * K;        C = Q;  Nc = 2048; n0 = bn * 256; }
    else if (bn < 10) { Bt = Wk + (size_t)(bn - 8) * 256 * K;  C = Kk; Nc = 512;  n0 = (bn - 8) * 256; }
    else              { Bt = Wv + (size_t)(bn - 10) * 256 * K; C = V;  Nc = 512;  n0 = (bn - 10) * 256; }

    const unsigned short* Ab = A + (size_t)m0 * K;

    f32x4 acc[8][4];
    #pragma unroll
    for (int mf = 0; mf < 8; ++mf)
        #pragma unroll
        for (int nf = 0; nf < 4; ++nf) acc[mf][nf] = (f32x4){0.f, 0.f, 0.f, 0.f};

    bf16x8 a[4][2], b0[2][2], b1[2][2];

    // stage one 128x64 half-tile (2 global_load_lds / thread)
    auto STAGE = [&](const unsigned short* __restrict__ G, int rb, int kc,
                     unsigned short* dst) {
        #pragma unroll
        for (int i = 0; i < 2; ++i) {
            int R = (w * 2 + i) * 8;
            async_copy16(G + (size_t)(rb + R + srow) * K + kc + schunk * 8,
                         dst + (size_t)R * 64);
        }
    };
    // mh selects the 128-row staging half; wave reads rows mh*128+wfm+...
    auto LDA = [&](int d, int mh) {
        #pragma unroll
        for (int mi = 0; mi < 4; ++mi) {
            int r = mh * 128 + wfm + mi * 16 + idx;
            #pragma unroll
            for (int ks = 0; ks < 2; ++ks)
                a[mi][ks] = *(const bf16x8*)&ldsA[d][r * 64 + (((ks * 4 + quad) ^ (r & 7)) << 3)];
        }
    };
    auto LDB0 = [&](int d, int nh) {
        #pragma unroll
        for (int nj = 0; nj < 2; ++nj) {
            int r = wfn + nh * 32 + nj * 16 + idx;
            #pragma unroll
            for (int ks = 0; ks < 2; ++ks)
                b0[nj][ks] = *(const bf16x8*)&ldsB[d][r * 64 + (((ks * 4 + quad) ^ (r & 7)) << 3)];
        }
    };
    auto LDB1 = [&](int d, int nh) {
        #pragma unroll
        for (int nj = 0; nj < 2; ++nj) {
            int r = wfn + nh * 32 + nj * 16 + idx;
            #pragma unroll
            for (int ks = 0; ks < 2; ++ks)
                b1[nj][ks] = *(const bf16x8*)&ldsB[d][r * 64 + (((ks * 4 + quad) ^ (r & 7)) << 3)];
        }
    };
    auto MM0 = [&](int mh, int nh) {   // quadrant with b0
        __builtin_amdgcn_s_setprio(1);
        #pragma unroll
        for (int mi = 0; mi < 4; ++mi)
            #pragma unroll
            for (int nj = 0; nj < 2; ++nj)
                #pragma unroll
                for (int ks = 0; ks < 2; ++ks)
                    acc[mh * 4 + mi][nh * 2 + nj] =
                        MFMA16(a[mi][ks], b0[nj][ks], acc[mh * 4 + mi][nh * 2 + nj]);
        __builtin_amdgcn_s_setprio(0);
    };
    auto MM1 = [&](int mh, int nh) {   // quadrant with b1
        __builtin_amdgcn_s_setprio(1);
        #pragma unroll
        for (int mi = 0; mi < 4; ++mi)
            #pragma unroll
            for (int nj = 0; nj < 2; ++nj)
                #pragma unroll
                for (int ks = 0; ks < 2; ++ks)
                    acc[mh * 4 + mi][nh * 2 + nj] =
                        MFMA16(a[mi][ks], b1[nj][ks], acc[mh * 4 + mi][nh * 2 + nj]);
        __builtin_amdgcn_s_setprio(0);
    };

    // ---- prologue: tile0 full into buf0, tile1 Alo/Blo/Bhi into buf1 ----
    STAGE(Ab, 0,   0,  &ldsA[0][0]);
    STAGE(Ab, 128, 0,  &ldsA[0][128 * 64]);
    STAGE(Bt, 0,   0,  &ldsB[0][0]);
    STAGE(Bt, 128, 0,  &ldsB[0][128 * 64]);
    STAGE(Ab, 0,   64, &ldsA[1][0]);
    STAGE(Bt, 0,   64, &ldsB[1][0]);
    STAGE(Bt, 128, 64, &ldsB[1][128 * 64]);
    VMCNT6();          // tile0 (8 oldest loads) landed; 6 outstanding
    BARRIER();

    // ---- main loop: 15 iters, tiles u=2it, u+1; stages u+2, u+3 (max 31) ----
    for (int it = 0; it < 15; ++it) {
        int u = 2 * it;
        // P1
        LDA(0, 0); LDB0(0, 0);
        STAGE(Ab, 128, (u + 1) * 64, &ldsA[1][128 * 64]);
        BARRIER(); MM0(0, 0); BARRIER();
        // P2
        LDB1(0, 1);
        STAGE(Ab, 0, (u + 2) * 64, &ldsA[0][0]);
        BARRIER(); MM1(0, 1); BARRIER();
        // P3
        LDA(0, 1);
        STAGE(Bt, 0, (u + 2) * 64, &ldsB[0][0]);
        BARRIER(); MM1(1, 1); BARRIER();
        // P4
        STAGE(Bt, 128, (u + 2) * 64, &ldsB[0][128 * 64]);
        VMCNT6();          // all of buf1 (tile u+1) landed
        BARRIER(); MM0(1, 0); BARRIER();
        // P5
        LDA(1, 0); LDB0(1, 0);
        STAGE(Ab, 128, (u + 2) * 64, &ldsA[0][128 * 64]);
        BARRIER(); MM0(0, 0); BARRIER();
        // P6
        LDB1(1, 1);
        STAGE(Ab, 0, (u + 3) * 64, &ldsA[1][0]);
        BARRIER(); MM1(0, 1); BARRIER();
        // P7
        LDA(1, 1);
        STAGE(Bt, 0, (u + 3) * 64, &ldsB[1][0]);
        BARRIER(); MM1(1, 1); BARRIER();
        // P8
        STAGE(Bt, 128, (u + 3) * 64, &ldsB[1][128 * 64]);
        VMCNT6();          // all of buf0 (tile u+2) landed
        BARRIER(); MM0(1, 0); BARRIER();
    }

    // ---- epilogue: tiles 30 (buf0), 31 (buf1); only stage left: b1.Ahi(31) ----
    LDA(0, 0); LDB0(0, 0);
    STAGE(Ab, 128, 31 * 64, &ldsA[1][128 * 64]);
    BARRIER(); MM0(0, 0); BARRIER();
    LDB1(0, 1);
    BARRIER(); MM1(0, 1); BARRIER();
    LDA(0, 1);
    BARRIER(); MM1(1, 1); BARRIER();
    VMCNT0();
    BARRIER(); MM0(1, 0); BARRIER();
    LDA(1, 0); LDB0(1, 0);
    BARRIER(); MM0(0, 0); BARRIER();
    LDB1(1, 1);
    BARRIER(); MM1(0, 1); BARRIER();
    LDA(1, 1);
    BARRIER(); MM1(1, 1); BARRIER();
    MM0(1, 0);

    // ---- C write: row half from mf>>2, offset wfm within half ----
    #pragma unroll
    for (int mf = 0; mf < 8; ++mf) {
        #pragma unroll
        for (int r = 0; r < 4; ++r) {
            size_t row = (size_t)(m0 + (mf >> 2) * 128 + wfm + (mf & 3) * 16 + quad * 4 + r);
            #pragma unroll
            for (int nf = 0; nf < 4; ++nf) {
                int col = n0 + wfn + nf * 16 + idx;
                C[row * Nc + col] = f2b(acc[mf][nf][r]);
            }
        }
    }
}

// ---------- tiled GEMM: C[M,N] = A[M,K] * Bt[N,K]^T (wo projection, dbuf) ----------
__device__ __forceinline__ void g_stage(
    const unsigned short* __restrict__ A, const unsigned short* __restrict__ Bt,
    unsigned short* As, unsigned short* Bs,
    int k0, int K, int w, int srow, int schunk)
{
    #pragma unroll
    for (int i = 0; i < 4; ++i) {
        int cb = w * 4 + i;
        size_t goff = (size_t)(cb * 8 + srow) * K + k0 + schunk * 8;
        async_copy16(A  + goff, &As[cb * 512]);
        async_copy16(Bt + goff, &Bs[cb * 512]);
    }
}
__device__ __forceinline__ void g_compute(
    const unsigned short* As, const unsigned short* Bs,
    f32x4 (&acc)[4][4], int wm, int wn, int idx, int quad)
{
    #pragma unroll
    for (int ks = 0; ks < 2; ++ks) {
        bf16x8 af[4], bfr[4];
        #pragma unroll
        for (int mi = 0; mi < 4; ++mi) {
            int row = wm + mi * 16 + idx;
            af[mi] = *(const bf16x8*)&As[row * 64 + (((ks * 4 + quad) ^ (row & 7)) * 8)];
        }
        #pragma unroll
        for (int ni = 0; ni < 4; ++ni) {
            int row = wn + ni * 16 + idx;
            bfr[ni] = *(const bf16x8*)&Bs[row * 64 + (((ks * 4 + quad) ^ (row & 7)) * 8)];
        }
        #pragma unroll
        for (int mi = 0; mi < 4; ++mi)
            #pragma unroll
            for (int ni = 0; ni < 4; ++ni)
                acc[mi][ni] = MFMA16(af[mi], bfr[ni], acc[mi][ni]);
    }
}

template <typename OutT>
__global__ __launch_bounds__(256) void gemm_tile(
    const unsigned short* __restrict__ A,
    const unsigned short* __restrict__ Bt,
    OutT* __restrict__ C,
    int M, int N, int K)
{
    constexpr int BK = 64;
    __shared__ unsigned short As0[128 * BK];
    __shared__ unsigned short Bs0[128 * BK];
    __shared__ unsigned short As1[128 * BK];
    __shared__ unsigned short Bs1[128 * BK];

    int tid  = threadIdx.x;
    int w    = tid >> 6;
    int lane = tid & 63;
    int idx  = lane & 15;
    int quad = lane >> 4;
    int wm   = (w >> 1) * 64;
    int wn   = (w & 1) * 64;

    int tilesN = N / 128;
    int bm = blockIdx.x / tilesN;
    int bn = blockIdx.x - bm * tilesN;
    int m0 = bm * 128, n0 = bn * 128;

    const unsigned short* Ab = A  + (size_t)m0 * K;
    const unsigned short* Bb = Bt + (size_t)n0 * K;

    int srow   = lane >> 3;
    int schunk = (lane & 7) ^ srow;

    f32x4 acc[4][4];
    #pragma unroll
    for (int mi = 0; mi < 4; ++mi)
        #pragma unroll
        for (int ni = 0; ni < 4; ++ni) acc[mi][ni] = (f32x4){0.f, 0.f, 0.f, 0.f};

    g_stage(Ab, Bb, As0, Bs0, 0, K, w, srow, schunk);
    __syncthreads();

    for (int k0 = 0; k0 < K; k0 += 2 * BK) {
        if (k0 + BK < K)
            g_stage(Ab, Bb, As1, Bs1, k0 + BK, K, w, srow, schunk);
        g_compute(As0, Bs0, acc, wm, wn, idx, quad);
        __syncthreads();
        if (k0 + 2 * BK < K)
            g_stage(Ab, Bb, As0, Bs0, k0 + 2 * BK, K, w, srow, schunk);
        g_compute(As1, Bs1, acc, wm, wn, idx, quad);
        __syncthreads();
    }

    #pragma unroll
    for (int mi = 0; mi < 4; ++mi) {
        #pragma unroll
        for (int r = 0; r < 4; ++r) {
            size_t row = (size_t)(m0 + wm + mi * 16 + quad * 4 + r);
            #pragma unroll
            for (int ni = 0; ni < 4; ++ni) {
                int col = n0 + wn + ni * 16 + idx;
                if constexpr (std::is_same_v<OutT, float>) {
                    C[row * N + col] = acc[mi][ni][r];
                } else {
                    C[row * N + col] = f2b(acc[mi][ni][r]);
                }
            }
        }
    }
}

// ---------- RoPE (in-place on bf16, f32 freqs; oscale folds attn scale into q) ----------
__global__ __launch_bounds__(256) void rope_kernel(
    unsigned short* __restrict__ x,
    const float* __restrict__ cs,
    const float* __restrict__ sn,
    int H, int total, float oscale)
{
    int e = blockIdx.x * blockDim.x + threadIdx.x;
    if (e >= total) return;
    int i = e & 63;
    int s = (e / (64 * H)) & 2047;   // S = 2048
    float xr = b2f(x[2 * e]);
    float xi = b2f(x[2 * e + 1]);
    float c  = cs[s * 64 + i];
    float sv = sn[s * 64 + i];
    x[2 * e]     = f2b((xr * c - xi * sv) * oscale);
    x[2 * e + 1] = f2b((xr * sv + xi * c) * oscale);
}

// ---------- MFMA flash attention v8: 512 blocks x 256 threads, KVBLK=64 ----------
// R8 post-mortem: occupancy 12.5% (4 waves/CU avg) -- heavy block (nt up to 64)
// runs mostly SOLO; makespan = its serial iteration chain (barrier + vmcnt +
// staging round per 32 keys). Fix: 64-key tiles -> iterations on the critical
// path HALVE (max nt 32, per-CU sum 34); per-iter compute doubles (64 MFMA +
// 2x softmax per wave), fully covering the ~900cy load latency issued at iter
// start. Per-key LDS bytes and K/V->2-q-group reuse unchanged.
// Ks 2x[64][128] XOR-chunk swizzled; Vt 2x[128][64+8] key-pair permuted per
// 32-key half (gk = hh*32 + (cc>>1) + 16*(cc&1)), slot-XOR swizzled.
// V staging: thread owns row pair (dp,dp+1) x slot w x both halves: 16 u32
// loads, 4 ds_write_b128 (no shuffles). 1 barrier/iter dbuf issue-early.
__global__ __launch_bounds__(256, 2) void flash_attn(
    const unsigned short* __restrict__ qg,
    const unsigned short* __restrict__ kk,
    const unsigned short* __restrict__ vv,
    unsigned short* __restrict__ out)
{
    const int S = 2048;
    int bid = blockIdx.x;
    int qp  = bid & 15;
    int bh  = bid >> 4;            // b*16 + h
    int h   = bh & 15;
    int b   = bh >> 4;
    int kvh = h >> 2;

    int p   = b ? (15 - qp) : qp;  // co-resident blocks sum to 34 iters

    int tid  = threadIdx.x;
    int w    = tid >> 6;           // 0..3
    int lane = tid & 63;
    int idx  = lane & 15;
    int quad = lane >> 4;

    int qt  = 2 * p + (w >> 1);    // waves 0-1: tile 2p, waves 2-3: tile 2p+1
    int wq0 = qt * 64 + (w & 1) * 32;   // wave owns rows wq0..wq0+31
    int qrA = wq0 + idx;                 // group A row; group B = +16

    __shared__ unsigned short Ks[2][64 * 128];   // XOR-chunk-swizzled rows
    __shared__ unsigned short Vt[2][128 * 72];   // V^T, per-half key-permuted

    const unsigned short* kbase = kk + ((size_t)b * S * 4 + kvh) * 128;
    const unsigned short* vbase = vv + ((size_t)b * S * 4 + kvh) * 128;

    // Q fragments for both groups (B-operand): lane idx = qrow
    bf16x8 qfA[4], qfB[4];
    {
        const unsigned short* qa =
            qg + ((size_t)((b * S + wq0 + idx) * 16 + h)) * 128 + quad * 8;
        const unsigned short* qb2 =
            qg + ((size_t)((b * S + wq0 + 16 + idx) * 16 + h)) * 128 + quad * 8;
        #pragma unroll
        for (int ko = 0; ko < 4; ++ko) {
            qfA[ko] = *(const bf16x8*)(qa  + ko * 32);
            qfB[ko] = *(const bf16x8*)(qb2 + ko * 32);
        }
    }

    f32x4 accA[8], accB[8];
    #pragma unroll
    for (int n = 0; n < 8; ++n) {
        accA[n] = (f32x4){0.f, 0.f, 0.f, 0.f};
        accB[n] = (f32x4){0.f, 0.f, 0.f, 0.f};
    }
    float lsumA = 0.f, lsumB = 0.f;

    // --- V staging: thread owns row pair (dp,dp+1), slot w, both halves ---
    int dp = lane * 2;
    int swzslot = ((w ^ ((dp >> 3) & 3)) << 3);

    int nt = 2 * p + 2;            // 64-key iterations; heavy tile needs (2p+2)*64 keys

    unsigned int vld[2][8];

    auto STAGE_ISSUE = [&](int t, int d) {
        #pragma unroll
        for (int i = 0; i < 4; ++i) {
            int key = w * 16 + i * 4 + (lane >> 4);
            int sc  = (lane & 15) ^ (key & 7);
            async_copy16(kbase + ((size_t)(t * 64 + key)) * 512 + sc * 8,
                         &Ks[d][(w * 16 + i * 4) * 128]);
        }
        const unsigned short* vc = vbase + ((size_t)t * 64) * 512 + dp;
        #pragma unroll
        for (int hh = 0; hh < 2; ++hh)
            #pragma unroll
            for (int ii = 0; ii < 8; ++ii) {
                int gk = hh * 32 + w * 4 + (ii >> 1) + 16 * (ii & 1);
                vld[hh][ii] = *(const unsigned int*)(vc + (size_t)gk * 512);
            }
    };
    auto STAGE_WRITE = [&](int d) {
        #pragma unroll
        for (int hh = 0; hh < 2; ++hh) {
            u16x8 lo, hi;
            #pragma unroll
            for (int ii = 0; ii < 8; ++ii) {
                lo[ii] = (unsigned short)vld[hh][ii];
                hi[ii] = (unsigned short)(vld[hh][ii] >> 16);
            }
            *(u16x8*)&Vt[d][dp * 72 + hh * 32 + swzslot]       = lo;
            *(u16x8*)&Vt[d][(dp + 1) * 72 + hh * 32 + swzslot] = hi;
        }
    };

    // ---- prologue: stage tile 0 into buf 0 ----
    STAGE_ISSUE(0, 0);
    VMCNT0();
    STAGE_WRITE(0);
    __syncthreads();

    // ---- main loop: 1 barrier / iteration ----
    for (int t = 0; t < nt; ++t) {
        int bc = t & 1;
        if (t + 1 < nt) STAGE_ISSUE(t + 1, bc ^ 1);

        if (t * 64 <= wq0 + 31) {   // tile within this wave's causal range
            // --- S^T = K·Q^T, 4 key-groups x 2 q-groups (K frags read ONCE) ---
            f32x4 sA[4], sB[4];
            #pragma unroll
            for (int g = 0; g < 4; ++g) {
                sA[g] = (f32x4){0.f, 0.f, 0.f, 0.f};
                sB[g] = (f32x4){0.f, 0.f, 0.f, 0.f};
            }
            #pragma unroll
            for (int ko = 0; ko < 4; ++ko) {
                int ch = ((ko * 4 + quad) ^ (idx & 7)) * 8;
                #pragma unroll
                for (int g = 0; g < 4; ++g) {
                    bf16x8 kf = *(const bf16x8*)&Ks[bc][(g * 16 + idx) * 128 + ch];
                    sA[g] = MFMA16(kf, qfA[ko], sA[g]);
                    sB[g] = MFMA16(kf, qfB[ko], sB[g]);
                }
            }
            // --- mask + exp2 (no max); per-half pk pairs = PV B-frags ---
            unsigned int pkA[2][4], pkB[2][4];
            if (t * 64 + 63 <= wq0) {          // full tile for all rows
                #pragma unroll
                for (int hh = 0; hh < 2; ++hh)
                    #pragma unroll
                    for (int r = 0; r < 4; ++r) {
                        float a0 = EXP2F(sA[hh * 2][r]), a1 = EXP2F(sA[hh * 2 + 1][r]);
                        float b0_ = EXP2F(sB[hh * 2][r]), b1_ = EXP2F(sB[hh * 2 + 1][r]);
                        lsumA += a0 + a1;
                        lsumB += b0_ + b1_;
                        pkA[hh][r] = (unsigned int)f2b(a0) | ((unsigned int)f2b(a1) << 16);
                        pkB[hh][r] = (unsigned int)f2b(b0_) | ((unsigned int)f2b(b1_) << 16);
                    }
            } else {                            // diagonal tile
                int LA = qrA - t * 64;
                int LB = LA + 16;
                #pragma unroll
                for (int hh = 0; hh < 2; ++hh)
                    #pragma unroll
                    for (int r = 0; r < 4; ++r) {
                        int kl = hh * 32 + quad * 4 + r;
                        float a0 = (kl      <= LA) ? EXP2F(sA[hh * 2][r]) : 0.f;
                        float a1 = (kl + 16 <= LA) ? EXP2F(sA[hh * 2 + 1][r]) : 0.f;
                        float b0_ = (kl      <= LB) ? EXP2F(sB[hh * 2][r]) : 0.f;
                        float b1_ = (kl + 16 <= LB) ? EXP2F(sB[hh * 2 + 1][r]) : 0.f;
                        lsumA += a0 + a1;
                        lsumB += b0_ + b1_;
                        pkA[hh][r] = (unsigned int)f2b(a0) | ((unsigned int)f2b(a1) << 16);
                        pkB[hh][r] = (unsigned int)f2b(b0_) | ((unsigned int)f2b(b1_) << 16);
                    }
            }
            u32x4 pA0 = {pkA[0][0], pkA[0][1], pkA[0][2], pkA[0][3]};
            u32x4 pA1 = {pkA[1][0], pkA[1][1], pkA[1][2], pkA[1][3]};
            u32x4 pB0 = {pkB[0][0], pkB[0][1], pkB[0][2], pkB[0][3]};
            u32x4 pB1 = {pkB[1][0], pkB[1][1], pkB[1][2], pkB[1][3]};
            bf16x8 pfA0 = __builtin_bit_cast(bf16x8, pA0);
            bf16x8 pfA1 = __builtin_bit_cast(bf16x8, pA1);
            bf16x8 pfB0 = __builtin_bit_cast(bf16x8, pB0);
            bf16x8 pfB1 = __builtin_bit_cast(bf16x8, pB1);
            // --- PV: O^T += V^T · P^T, per half (V frags feed both q-groups) ---
            #pragma unroll
            for (int n = 0; n < 8; ++n) {
                int rr = n * 16 + idx;
                int base = rr * 72 + ((quad ^ ((rr >> 3) & 3)) << 3);
                bf16x8 vf0 = *(const bf16x8*)&Vt[bc][base];
                bf16x8 vf1 = *(const bf16x8*)&Vt[bc][base + 32];
                accA[n] = MFMA16(vf0, pfA0, accA[n]);
                accA[n] = MFMA16(vf1, pfA1, accA[n]);
                accB[n] = MFMA16(vf0, pfB0, accB[n]);
                accB[n] = MFMA16(vf1, pfB1, accB[n]);
            }
        }

        if (t + 1 < nt) {
            VMCNT0();               // V regs + K DMA (issued pre-compute) landed
            STAGE_WRITE(bc ^ 1);
        }
        __syncthreads();            // tile t+1 ready; buf writes visible
    }

    // --- epilogue ---
    lsumA += __shfl_xor(lsumA, 16);
    lsumA += __shfl_xor(lsumA, 32);
    lsumB += __shfl_xor(lsumB, 16);
    lsumB += __shfl_xor(lsumB, 32);
    float invA = 1.f / lsumA;
    float invB = 1.f / lsumB;
    size_t rowA = (size_t)(b * S + wq0 + idx) * 2048 + h * 128;
    size_t rowB = rowA + (size_t)16 * 2048;
    #pragma unroll
    for (int n = 0; n < 8; ++n) {
        ushort4 oA, oB;
        oA.x = f2b(accA[n][0] * invA);
        oA.y = f2b(accA[n][1] * invA);
        oA.z = f2b(accA[n][2] * invA);
        oA.w = f2b(accA[n][3] * invA);
        oB.x = f2b(accB[n][0] * invB);
        oB.y = f2b(accB[n][1] * invB);
        oB.z = f2b(accB[n][2] * invB);
        oB.w = f2b(accB[n][3] * invB);
        *(ushort4*)&out[rowA + n * 16 + quad * 4] = oA;
        *(ushort4*)&out[rowB + n * 16 + quad * 4] = oB;
    }
}

// ---------- launch ----------
extern "C" void kernel_launch(void* const* d_in, const int* in_sizes, int n_in,
                              void* d_out, int out_size, void* d_ws, size_t ws_size,
                              hipStream_t stream)
{
    const float* x  = (const float*)d_in[0];
    const float* fc = (const float*)d_in[1];
    const float* fs = (const float*)d_in[2];
    const float* wq = (const float*)d_in[3];
    const float* wk = (const float*)d_in[4];
    const float* wv = (const float*)d_in[5];
    const float* wo = (const float*)d_in[6];
    float* out = (float*)d_out;

    const int B = 2, S = 2048, D = 2048, KV = 512;
    const int M = B * S;                 // 4096

    unsigned short* ws  = (unsigned short*)d_ws;
    unsigned short* xb  = ws;                         // 4096*2048
    unsigned short* wqb = xb  + (size_t)M * D;        // 2048*2048
    unsigned short* wkb = wqb + (size_t)D * D;        // 512*2048
    unsigned short* wvb = wkb + (size_t)KV * D;       // 512*2048
    unsigned short* wob = wvb + (size_t)KV * D;       // 2048*2048
    unsigned short* qb  = wob + (size_t)D * D;        // 4096*2048
    unsigned short* kb  = qb  + (size_t)M * D;        // 4096*512
    unsigned short* vb  = kb  + (size_t)M * KV;       // 4096*512
    unsigned short* ao  = vb  + (size_t)M * KV;       // 4096*2048

    cvt_f32_to_bf16<<<dim3((M * D / 4) / 256), dim3(256), 0, stream>>>(x,  xb,  M * D / 4);
    cvt_f32_to_bf16<<<dim3((D * D / 4) / 256), dim3(256), 0, stream>>>(wq, wqb, D * D / 4);
    cvt_f32_to_bf16<<<dim3((KV * D / 4) / 256), dim3(256), 0, stream>>>(wk, wkb, KV * D / 4);
    cvt_f32_to_bf16<<<dim3((KV * D / 4) / 256), dim3(256), 0, stream>>>(wv, wvb, KV * D / 4);
    cvt_f32_to_bf16<<<dim3((D * D / 4) / 256), dim3(256), 0, stream>>>(wo, wob, D * D / 4);

    // fused QKV projection: 16 m-tiles x 12 n-tiles = 192 blocks, 512 thr
    qkv_gemm<<<dim3(192), dim3(512), 0, stream>>>(xb, wqb, wkb, wvb, qb, kb, vb);

    int qpairs = B * S * 16 * 64;
    int kpairs = B * S * 4 * 64;
    const float c2 = 0.12752584f;   // (1/sqrt(128)) * log2(e), folded into q
    rope_kernel<<<dim3(qpairs / 256), dim3(256), 0, stream>>>(qb, fc, fs, 16, qpairs, c2);
    rope_kernel<<<dim3(kpairs / 256), dim3(256), 0, stream>>>(kb, fc, fs, 4, kpairs, 1.0f);

    // flash attention: 512 blocks x 256 threads (4 waves, KVBLK=64)
    flash_attn<<<dim3(512), dim3(256), 0, stream>>>(qb, kb, vb, ao);

    gemm_tile<float><<<dim3((M / 128) * (D / 128)), dim3(256), 0, stream>>>(ao, wob, out, M, D, D);
}

// Round 10
// 305.266 us; speedup vs baseline: 1.0703x; 1.0250x over previous
//
#include <hip/hip_runtime.h>
#include <hip/hip_bf16.h>
#include <type_traits>

// ---------- types / helpers ----------
using bf16x8 = __attribute__((ext_vector_type(8))) short;   // 8 bf16 in 4 VGPRs
using f32x4  = __attribute__((ext_vector_type(4))) float;
using u16x8  = __attribute__((ext_vector_type(8))) unsigned short;
using u16x4  = __attribute__((ext_vector_type(4))) unsigned short;
using u32x4  = __attribute__((ext_vector_type(4))) unsigned int;

__device__ __forceinline__ float b2f(unsigned short u) {
    unsigned int x = ((unsigned int)u) << 16;
    return __builtin_bit_cast(float, x);
}
__device__ __forceinline__ unsigned short f2b(float f) {
    __hip_bfloat16 h = __float2bfloat16(f);   // RN
    return __builtin_bit_cast(unsigned short, h);
}

// exp2: bounded-domain scores, hardware v_exp_f32 either way
#if defined(__has_builtin)
#if __has_builtin(__builtin_amdgcn_exp2f)
#define EXP2F(x) __builtin_amdgcn_exp2f(x)
#else
#define EXP2F(x) exp2f(x)
#endif
#else
#define EXP2F(x) exp2f(x)
#endif

// async global->LDS, 16 B per lane; LDS dest is wave-uniform base + lane*16
__device__ __forceinline__ void async_copy16(const void* g, void* l) {
    __builtin_amdgcn_global_load_lds(
        (const __attribute__((address_space(1))) unsigned int*)g,
        (__attribute__((address_space(3))) unsigned int*)l, 16, 0, 0);
}

#define MFMA16(a, b, c) __builtin_amdgcn_mfma_f32_16x16x32_bf16(a, b, c, 0, 0, 0)

// raw barrier with compiler memory fence (no vmcnt/lgkmcnt drain)
#define BARRIER() do { asm volatile("" ::: "memory"); \
    __builtin_amdgcn_s_barrier(); asm volatile("" ::: "memory"); } while (0)
#define VMCNT6() asm volatile("s_waitcnt vmcnt(6)" ::: "memory")
#define VMCNT0() asm volatile("s_waitcnt vmcnt(0)" ::: "memory")

// ---------- f32 -> bf16 conversion (4 elems/thread) ----------
__global__ __launch_bounds__(256) void cvt_f32_to_bf16(
    const float* __restrict__ s, unsigned short* __restrict__ d, int n4)
{
    int i = blockIdx.x * blockDim.x + threadIdx.x;
    if (i >= n4) return;
    float4 v = ((const float4*)s)[i];
    ushort4 o;
    o.x = f2b(v.x); o.y = f2b(v.y); o.z = f2b(v.z); o.w = f2b(v.w);
    ((ushort4*)d)[i] = o;
}

// ---------- fused QKV GEMM, 256x256 8-phase template (T3+T4+T5) ----------
// [Q|K|V] = x @ [wq;wk;wv]^T.  M=4096, Ntot=3072, K=2048.
// Grid 16m x 12n = 192 blocks, 512 threads (8 waves), BK=64.
// LDS 128KB: 2 dbuf x (A,B) x 256x64 bf16, staged in 128-row halves.
// Wave m: wfm=(w>>2)*64; halves {wfm..} (A-low, P1) / {128+wfm..} (A-high, P3).
// R9 refinement: per-phase ds_read distribution rebalanced 12/4/8/0 ->
// 8/4/8/4 (m201-matching) by moving the LDB0 read into the vmcnt phases
// P4/P8 (buffer guaranteed landed there) with ping-pong register sets
// b0A/b0B so P4's MFMA still sees the old fragments. LDS choreography
// (stage targets, vmcnt placement, barriers) unchanged from the R9
// passing kernel. vmcnt(6) ONLY at P4/P8 (3 half-tiles in flight).
__global__ __launch_bounds__(512, 2) void qkv_gemm(
    const unsigned short* __restrict__ A,    // M x 2048
    const unsigned short* __restrict__ Wq,   // 2048 x 2048
    const unsigned short* __restrict__ Wk,   // 512 x 2048
    const unsigned short* __restrict__ Wv,   // 512 x 2048
    unsigned short* __restrict__ Q,          // M x 2048
    unsigned short* __restrict__ Kk,         // M x 512
    unsigned short* __restrict__ V)          // M x 512
{
    const int K = 2048;
    __shared__ unsigned short ldsA[2][256 * 64];
    __shared__ unsigned short ldsB[2][256 * 64];

    int tid  = threadIdx.x;
    int w    = tid >> 6;           // 0..7
    int lane = tid & 63;
    int idx  = lane & 15;
    int quad = lane >> 4;
    int srow   = lane >> 3;
    int schunk = (lane & 7) ^ srow;

    int wfm = (w >> 2) * 64;       // wave m-offset within each 128-row half
    int wfn = (w & 3) * 64;        // wave n-offset

    // XCD-contiguous swizzle (192 % 8 == 0, bijective)
    int bid = (blockIdx.x & 7) * 24 + (blockIdx.x >> 3);
    int bm = bid / 12;
    int bn = bid - bm * 12;
    int m0 = bm * 256;

    const unsigned short* Bt;
    unsigned short* C;
    int Nc, n0;
    if (bn < 8)       { Bt = Wq + (size_t)bn * 256 * K;        C = Q;  Nc = 2048; n0 = bn * 256; }
    else if (bn < 10) { Bt = Wk + (size_t)(bn - 8) * 256 * K;  C = Kk; Nc = 512;  n0 = (bn - 8) * 256; }
    else              { Bt = Wv + (size_t)(bn - 10) * 256 * K; C = V;  Nc = 512;  n0 = (bn - 10) * 256; }

    const unsigned short* Ab = A + (size_t)m0 * K;

    f32x4 acc[8][4];
    #pragma unroll
    for (int mf = 0; mf < 8; ++mf)
        #pragma unroll
        for (int nf = 0; nf < 4; ++nf) acc[mf][nf] = (f32x4){0.f, 0.f, 0.f, 0.f};

    bf16x8 a[4][2], b0A[2][2], b0B[2][2], b1[2][2];

    // stage one 128x64 half-tile (2 global_load_lds / thread)
    auto STAGE = [&](const unsigned short* __restrict__ G, int rb, int kc,
                     unsigned short* dst) {
        #pragma unroll
        for (int i = 0; i < 2; ++i) {
            int R = (w * 2 + i) * 8;
            async_copy16(G + (size_t)(rb + R + srow) * K + kc + schunk * 8,
                         dst + (size_t)R * 64);
        }
    };
    // mh selects the 128-row staging half; wave reads rows mh*128+wfm+...
    auto LDA = [&](int d, int mh) {
        #pragma unroll
        for (int mi = 0; mi < 4; ++mi) {
            int r = mh * 128 + wfm + mi * 16 + idx;
            #pragma unroll
            for (int ks = 0; ks < 2; ++ks)
                a[mi][ks] = *(const bf16x8*)&ldsA[d][r * 64 + (((ks * 4 + quad) ^ (r & 7)) << 3)];
        }
    };
    auto LDB0 = [&](int d, int nh, bf16x8 (&bb)[2][2]) {
        #pragma unroll
        for (int nj = 0; nj < 2; ++nj) {
            int r = wfn + nh * 32 + nj * 16 + idx;
            #pragma unroll
            for (int ks = 0; ks < 2; ++ks)
                bb[nj][ks] = *(const bf16x8*)&ldsB[d][r * 64 + (((ks * 4 + quad) ^ (r & 7)) << 3)];
        }
    };
    auto LDB1 = [&](int d, int nh) {
        #pragma unroll
        for (int nj = 0; nj < 2; ++nj) {
            int r = wfn + nh * 32 + nj * 16 + idx;
            #pragma unroll
            for (int ks = 0; ks < 2; ++ks)
                b1[nj][ks] = *(const bf16x8*)&ldsB[d][r * 64 + (((ks * 4 + quad) ^ (r & 7)) << 3)];
        }
    };
    auto MM0 = [&](int mh, int nh, bf16x8 (&bb)[2][2]) {   // quadrant with b0 set
        __builtin_amdgcn_s_setprio(1);
        #pragma unroll
        for (int mi = 0; mi < 4; ++mi)
            #pragma unroll
            for (int nj = 0; nj < 2; ++nj)
                #pragma unroll
                for (int ks = 0; ks < 2; ++ks)
                    acc[mh * 4 + mi][nh * 2 + nj] =
                        MFMA16(a[mi][ks], bb[nj][ks], acc[mh * 4 + mi][nh * 2 + nj]);
        __builtin_amdgcn_s_setprio(0);
    };
    auto MM1 = [&](int mh, int nh) {   // quadrant with b1
        __builtin_amdgcn_s_setprio(1);
        #pragma unroll
        for (int mi = 0; mi < 4; ++mi)
            #pragma unroll
            for (int nj = 0; nj < 2; ++nj)
                #pragma unroll
                for (int ks = 0; ks < 2; ++ks)
                    acc[mh * 4 + mi][nh * 2 + nj] =
                        MFMA16(a[mi][ks], b1[nj][ks], acc[mh * 4 + mi][nh * 2 + nj]);
        __builtin_amdgcn_s_setprio(0);
    };

    // ---- prologue: tile0 full into buf0, tile1 Alo/Blo/Bhi into buf1 ----
    STAGE(Ab, 0,   0,  &ldsA[0][0]);
    STAGE(Ab, 128, 0,  &ldsA[0][128 * 64]);
    STAGE(Bt, 0,   0,  &ldsB[0][0]);
    STAGE(Bt, 128, 0,  &ldsB[0][128 * 64]);
    STAGE(Ab, 0,   64, &ldsA[1][0]);
    STAGE(Bt, 0,   64, &ldsB[1][0]);
    STAGE(Bt, 128, 64, &ldsB[1][128 * 64]);
    VMCNT6();          // tile0 (8 oldest loads) landed; 6 outstanding
    BARRIER();
    LDB0(0, 0, b0A);   // pre-load loop-carried B-lo fragments (buf0, tile0)

    // ---- main loop: 15 iters, tiles u=2it, u+1; stages u+2, u+3 (max 31) ----
    for (int it = 0; it < 15; ++it) {
        int u = 2 * it;
        // P1  (8 ds_read)
        LDA(0, 0);
        STAGE(Ab, 128, (u + 1) * 64, &ldsA[1][128 * 64]);
        BARRIER(); MM0(0, 0, b0A); BARRIER();
        // P2  (4 ds_read)
        LDB1(0, 1);
        STAGE(Ab, 0, (u + 2) * 64, &ldsA[0][0]);
        BARRIER(); MM1(0, 1); BARRIER();
        // P3  (8 ds_read)
        LDA(0, 1);
        STAGE(Bt, 0, (u + 2) * 64, &ldsB[0][0]);
        BARRIER(); MM1(1, 1); BARRIER();
        // P4  (4 ds_read, post-vmcnt)
        STAGE(Bt, 128, (u + 2) * 64, &ldsB[0][128 * 64]);
        VMCNT6();              // all of buf1 (tile u+1) landed
        LDB0(1, 0, b0B);       // read buf1 B-lo for P5 (MFMA below uses b0A)
        BARRIER(); MM0(1, 0, b0A); BARRIER();
        // P5  (8 ds_read)
        LDA(1, 0);
        STAGE(Ab, 128, (u + 2) * 64, &ldsA[0][128 * 64]);
        BARRIER(); MM0(0, 0, b0B); BARRIER();
        // P6  (4 ds_read)
        LDB1(1, 1);
        STAGE(Ab, 0, (u + 3) * 64, &ldsA[1][0]);
        BARRIER(); MM1(0, 1); BARRIER();
        // P7  (8 ds_read)
        LDA(1, 1);
        STAGE(Bt, 0, (u + 3) * 64, &ldsB[1][0]);
        BARRIER(); MM1(1, 1); BARRIER();
        // P8  (4 ds_read, post-vmcnt)
        STAGE(Bt, 128, (u + 3) * 64, &ldsB[1][128 * 64]);
        VMCNT6();              // all of buf0 (tile u+2) landed
        LDB0(0, 0, b0A);       // read buf0 B-lo for next-iter P1
        BARRIER(); MM0(1, 0, b0B); BARRIER();
    }

    // ---- epilogue: tiles 30 (buf0), 31 (buf1); b0A carried from last P8 ----
    LDA(0, 0);
    STAGE(Ab, 128, 31 * 64, &ldsA[1][128 * 64]);
    BARRIER(); MM0(0, 0, b0A); BARRIER();
    LDB1(0, 1);
    BARRIER(); MM1(0, 1); BARRIER();
    LDA(0, 1);
    BARRIER(); MM1(1, 1); BARRIER();
    VMCNT0();                  // everything landed (incl. b1.Ahi(31))
    LDB0(1, 0, b0B);
    BARRIER(); MM0(1, 0, b0A); BARRIER();
    LDA(1, 0);
    BARRIER(); MM0(0, 0, b0B); BARRIER();
    LDB1(1, 1);
    BARRIER(); MM1(0, 1); BARRIER();
    LDA(1, 1);
    BARRIER(); MM1(1, 1); BARRIER();
    MM0(1, 0, b0B);

    // ---- C write: row half from mf>>2, offset wfm within half ----
    #pragma unroll
    for (int mf = 0; mf < 8; ++mf) {
        #pragma unroll
        for (int r = 0; r < 4; ++r) {
            size_t row = (size_t)(m0 + (mf >> 2) * 128 + wfm + (mf & 3) * 16 + quad * 4 + r);
            #pragma unroll
            for (int nf = 0; nf < 4; ++nf) {
                int col = n0 + wfn + nf * 16 + idx;
                C[row * Nc + col] = f2b(acc[mf][nf][r]);
            }
        }
    }
}

// ---------- tiled GEMM: C[M,N] = A[M,K] * Bt[N,K]^T (wo projection, dbuf) ----------
__device__ __forceinline__ void g_stage(
    const unsigned short* __restrict__ A, const unsigned short* __restrict__ Bt,
    unsigned short* As, unsigned short* Bs,
    int k0, int K, int w, int srow, int schunk)
{
    #pragma unroll
    for (int i = 0; i < 4; ++i) {
        int cb = w * 4 + i;
        size_t goff = (size_t)(cb * 8 + srow) * K + k0 + schunk * 8;
        async_copy16(A  + goff, &As[cb * 512]);
        async_copy16(Bt + goff, &Bs[cb * 512]);
    }
}
__device__ __forceinline__ void g_compute(
    const unsigned short* As, const unsigned short* Bs,
    f32x4 (&acc)[4][4], int wm, int wn, int idx, int quad)
{
    #pragma unroll
    for (int ks = 0; ks < 2; ++ks) {
        bf16x8 af[4], bfr[4];
        #pragma unroll
        for (int mi = 0; mi < 4; ++mi) {
            int row = wm + mi * 16 + idx;
            af[mi] = *(const bf16x8*)&As[row * 64 + (((ks * 4 + quad) ^ (row & 7)) * 8)];
        }
        #pragma unroll
        for (int ni = 0; ni < 4; ++ni) {
            int row = wn + ni * 16 + idx;
            bfr[ni] = *(const bf16x8*)&Bs[row * 64 + (((ks * 4 + quad) ^ (row & 7)) * 8)];
        }
        #pragma unroll
        for (int mi = 0; mi < 4; ++mi)
            #pragma unroll
            for (int ni = 0; ni < 4; ++ni)
                acc[mi][ni] = MFMA16(af[mi], bfr[ni], acc[mi][ni]);
    }
}

template <typename OutT>
__global__ __launch_bounds__(256) void gemm_tile(
    const unsigned short* __restrict__ A,
    const unsigned short* __restrict__ Bt,
    OutT* __restrict__ C,
    int M, int N, int K)
{
    constexpr int BK = 64;
    __shared__ unsigned short As0[128 * BK];
    __shared__ unsigned short Bs0[128 * BK];
    __shared__ unsigned short As1[128 * BK];
    __shared__ unsigned short Bs1[128 * BK];

    int tid  = threadIdx.x;
    int w    = tid >> 6;
    int lane = tid & 63;
    int idx  = lane & 15;
    int quad = lane >> 4;
    int wm   = (w >> 1) * 64;
    int wn   = (w & 1) * 64;

    int tilesN = N / 128;
    int bm = blockIdx.x / tilesN;
    int bn = blockIdx.x - bm * tilesN;
    int m0 = bm * 128, n0 = bn * 128;

    const unsigned short* Ab = A  + (size_t)m0 * K;
    const unsigned short* Bb = Bt + (size_t)n0 * K;

    int srow   = lane >> 3;
    int schunk = (lane & 7) ^ srow;

    f32x4 acc[4][4];
    #pragma unroll
    for (int mi = 0; mi < 4; ++mi)
        #pragma unroll
        for (int ni = 0; ni < 4; ++ni) acc[mi][ni] = (f32x4){0.f, 0.f, 0.f, 0.f};

    g_stage(Ab, Bb, As0, Bs0, 0, K, w, srow, schunk);
    __syncthreads();

    for (int k0 = 0; k0 < K; k0 += 2 * BK) {
        if (k0 + BK < K)
            g_stage(Ab, Bb, As1, Bs1, k0 + BK, K, w, srow, schunk);
        g_compute(As0, Bs0, acc, wm, wn, idx, quad);
        __syncthreads();
        if (k0 + 2 * BK < K)
            g_stage(Ab, Bb, As0, Bs0, k0 + 2 * BK, K, w, srow, schunk);
        g_compute(As1, Bs1, acc, wm, wn, idx, quad);
        __syncthreads();
    }

    #pragma unroll
    for (int mi = 0; mi < 4; ++mi) {
        #pragma unroll
        for (int r = 0; r < 4; ++r) {
            size_t row = (size_t)(m0 + wm + mi * 16 + quad * 4 + r);
            #pragma unroll
            for (int ni = 0; ni < 4; ++ni) {
                int col = n0 + wn + ni * 16 + idx;
                if constexpr (std::is_same_v<OutT, float>) {
                    C[row * N + col] = acc[mi][ni][r];
                } else {
                    C[row * N + col] = f2b(acc[mi][ni][r]);
                }
            }
        }
    }
}

// ---------- RoPE (in-place on bf16, f32 freqs; oscale folds attn scale into q) ----------
__global__ __launch_bounds__(256) void rope_kernel(
    unsigned short* __restrict__ x,
    const float* __restrict__ cs,
    const float* __restrict__ sn,
    int H, int total, float oscale)
{
    int e = blockIdx.x * blockDim.x + threadIdx.x;
    if (e >= total) return;
    int i = e & 63;
    int s = (e / (64 * H)) & 2047;   // S = 2048
    float xr = b2f(x[2 * e]);
    float xi = b2f(x[2 * e + 1]);
    float c  = cs[s * 64 + i];
    float sv = sn[s * 64 + i];
    x[2 * e]     = f2b((xr * c - xi * sv) * oscale);
    x[2 * e + 1] = f2b((xr * sv + xi * c) * oscale);
}

// ---------- MFMA flash attention v8: 512 blocks x 256 threads, KVBLK=64 ----------
// 4 waves; wave w: tile 2p+(w>>1), rows wq0..wq0+31 (two 16-row groups A/B
// sharing each K/V fragment read). 64-key tiles halve the serial iteration
// chain (max nt 32); per-iter compute doubles, covering issued-early loads.
// Ks 2x[64][128] XOR-chunk swizzled; Vt 2x[128][64+8] per-half key-permuted.
// V staging: thread owns row pair x slot w x both halves; 4 ds_write_b128,
// no shuffles. 1 barrier/iter dbuf issue-early.
__global__ __launch_bounds__(256, 2) void flash_attn(
    const unsigned short* __restrict__ qg,
    const unsigned short* __restrict__ kk,
    const unsigned short* __restrict__ vv,
    unsigned short* __restrict__ out)
{
    const int S = 2048;
    int bid = blockIdx.x;
    int qp  = bid & 15;
    int bh  = bid >> 4;            // b*16 + h
    int h   = bh & 15;
    int b   = bh >> 4;
    int kvh = h >> 2;

    int p   = b ? (15 - qp) : qp;  // co-resident blocks sum to 34 iters

    int tid  = threadIdx.x;
    int w    = tid >> 6;           // 0..3
    int lane = tid & 63;
    int idx  = lane & 15;
    int quad = lane >> 4;

    int qt  = 2 * p + (w >> 1);    // waves 0-1: tile 2p, waves 2-3: tile 2p+1
    int wq0 = qt * 64 + (w & 1) * 32;   // wave owns rows wq0..wq0+31
    int qrA = wq0 + idx;                 // group A row; group B = +16

    __shared__ unsigned short Ks[2][64 * 128];   // XOR-chunk-swizzled rows
    __shared__ unsigned short Vt[2][128 * 72];   // V^T, per-half key-permuted

    const unsigned short* kbase = kk + ((size_t)b * S * 4 + kvh) * 128;
    const unsigned short* vbase = vv + ((size_t)b * S * 4 + kvh) * 128;

    // Q fragments for both groups (B-operand): lane idx = qrow
    bf16x8 qfA[4], qfB[4];
    {
        const unsigned short* qa =
            qg + ((size_t)((b * S + wq0 + idx) * 16 + h)) * 128 + quad * 8;
        const unsigned short* qb2 =
            qg + ((size_t)((b * S + wq0 + 16 + idx) * 16 + h)) * 128 + quad * 8;
        #pragma unroll
        for (int ko = 0; ko < 4; ++ko) {
            qfA[ko] = *(const bf16x8*)(qa  + ko * 32);
            qfB[ko] = *(const bf16x8*)(qb2 + ko * 32);
        }
    }

    f32x4 accA[8], accB[8];
    #pragma unroll
    for (int n = 0; n < 8; ++n) {
        accA[n] = (f32x4){0.f, 0.f, 0.f, 0.f};
        accB[n] = (f32x4){0.f, 0.f, 0.f, 0.f};
    }
    float lsumA = 0.f, lsumB = 0.f;

    // --- V staging: thread owns row pair (dp,dp+1), slot w, both halves ---
    int dp = lane * 2;
    int swzslot = ((w ^ ((dp >> 3) & 3)) << 3);

    int nt = 2 * p + 2;            // 64-key iterations

    unsigned int vld[2][8];

    auto STAGE_ISSUE = [&](int t, int d) {
        #pragma unroll
        for (int i = 0; i < 4; ++i) {
            int key = w * 16 + i * 4 + (lane >> 4);
            int sc  = (lane & 15) ^ (key & 7);
            async_copy16(kbase + ((size_t)(t * 64 + key)) * 512 + sc * 8,
                         &Ks[d][(w * 16 + i * 4) * 128]);
        }
        const unsigned short* vc = vbase + ((size_t)t * 64) * 512 + dp;
        #pragma unroll
        for (int hh = 0; hh < 2; ++hh)
            #pragma unroll
            for (int ii = 0; ii < 8; ++ii) {
                int gk = hh * 32 + w * 4 + (ii >> 1) + 16 * (ii & 1);
                vld[hh][ii] = *(const unsigned int*)(vc + (size_t)gk * 512);
            }
    };
    auto STAGE_WRITE = [&](int d) {
        #pragma unroll
        for (int hh = 0; hh < 2; ++hh) {
            u16x8 lo, hi;
            #pragma unroll
            for (int ii = 0; ii < 8; ++ii) {
                lo[ii] = (unsigned short)vld[hh][ii];
                hi[ii] = (unsigned short)(vld[hh][ii] >> 16);
            }
            *(u16x8*)&Vt[d][dp * 72 + hh * 32 + swzslot]       = lo;
            *(u16x8*)&Vt[d][(dp + 1) * 72 + hh * 32 + swzslot] = hi;
        }
    };

    // ---- prologue: stage tile 0 into buf 0 ----
    STAGE_ISSUE(0, 0);
    VMCNT0();
    STAGE_WRITE(0);
    __syncthreads();

    // ---- main loop: 1 barrier / iteration ----
    for (int t = 0; t < nt; ++t) {
        int bc = t & 1;
        if (t + 1 < nt) STAGE_ISSUE(t + 1, bc ^ 1);

        if (t * 64 <= wq0 + 31) {   // tile within this wave's causal range
            // --- S^T = K·Q^T, 4 key-groups x 2 q-groups (K frags read ONCE) ---
            f32x4 sA[4], sB[4];
            #pragma unroll
            for (int g = 0; g < 4; ++g) {
                sA[g] = (f32x4){0.f, 0.f, 0.f, 0.f};
                sB[g] = (f32x4){0.f, 0.f, 0.f, 0.f};
            }
            #pragma unroll
            for (int ko = 0; ko < 4; ++ko) {
                int ch = ((ko * 4 + quad) ^ (idx & 7)) * 8;
                #pragma unroll
                for (int g = 0; g < 4; ++g) {
                    bf16x8 kf = *(const bf16x8*)&Ks[bc][(g * 16 + idx) * 128 + ch];
                    sA[g] = MFMA16(kf, qfA[ko], sA[g]);
                    sB[g] = MFMA16(kf, qfB[ko], sB[g]);
                }
            }
            // --- mask + exp2 (no max); per-half pk pairs = PV B-frags ---
            unsigned int pkA[2][4], pkB[2][4];
            if (t * 64 + 63 <= wq0) {          // full tile for all rows
                #pragma unroll
                for (int hh = 0; hh < 2; ++hh)
                    #pragma unroll
                    for (int r = 0; r < 4; ++r) {
                        float a0 = EXP2F(sA[hh * 2][r]), a1 = EXP2F(sA[hh * 2 + 1][r]);
                        float b0_ = EXP2F(sB[hh * 2][r]), b1_ = EXP2F(sB[hh * 2 + 1][r]);
                        lsumA += a0 + a1;
                        lsumB += b0_ + b1_;
                        pkA[hh][r] = (unsigned int)f2b(a0) | ((unsigned int)f2b(a1) << 16);
                        pkB[hh][r] = (unsigned int)f2b(b0_) | ((unsigned int)f2b(b1_) << 16);
                    }
            } else {                            // diagonal tile
                int LA = qrA - t * 64;
                int LB = LA + 16;
                #pragma unroll
                for (int hh = 0; hh < 2; ++hh)
                    #pragma unroll
                    for (int r = 0; r < 4; ++r) {
                        int kl = hh * 32 + quad * 4 + r;
                        float a0 = (kl      <= LA) ? EXP2F(sA[hh * 2][r]) : 0.f;
                        float a1 = (kl + 16 <= LA) ? EXP2F(sA[hh * 2 + 1][r]) : 0.f;
                        float b0_ = (kl      <= LB) ? EXP2F(sB[hh * 2][r]) : 0.f;
                        float b1_ = (kl + 16 <= LB) ? EXP2F(sB[hh * 2 + 1][r]) : 0.f;
                        lsumA += a0 + a1;
                        lsumB += b0_ + b1_;
                        pkA[hh][r] = (unsigned int)f2b(a0) | ((unsigned int)f2b(a1) << 16);
                        pkB[hh][r] = (unsigned int)f2b(b0_) | ((unsigned int)f2b(b1_) << 16);
                    }
            }
            u32x4 pA0 = {pkA[0][0], pkA[0][1], pkA[0][2], pkA[0][3]};
            u32x4 pA1 = {pkA[1][0], pkA[1][1], pkA[1][2], pkA[1][3]};
            u32x4 pB0 = {pkB[0][0], pkB[0][1], pkB[0][2], pkB[0][3]};
            u32x4 pB1 = {pkB[1][0], pkB[1][1], pkB[1][2], pkB[1][3]};
            bf16x8 pfA0 = __builtin_bit_cast(bf16x8, pA0);
            bf16x8 pfA1 = __builtin_bit_cast(bf16x8, pA1);
            bf16x8 pfB0 = __builtin_bit_cast(bf16x8, pB0);
            bf16x8 pfB1 = __builtin_bit_cast(bf16x8, pB1);
            // --- PV: O^T += V^T · P^T, per half (V frags feed both q-groups) ---
            #pragma unroll
            for (int n = 0; n < 8; ++n) {
                int rr = n * 16 + idx;
                int base = rr * 72 + ((quad ^ ((rr >> 3) & 3)) << 3);
                bf16x8 vf0 = *(const bf16x8*)&Vt[bc][base];
                bf16x8 vf1 = *(const bf16x8*)&Vt[bc][base + 32];
                accA[n] = MFMA16(vf0, pfA0, accA[n]);
                accA[n] = MFMA16(vf1, pfA1, accA[n]);
                accB[n] = MFMA16(vf0, pfB0, accB[n]);
                accB[n] = MFMA16(vf1, pfB1, accB[n]);
            }
        }

        if (t + 1 < nt) {
            VMCNT0();               // V regs + K DMA (issued pre-compute) landed
            STAGE_WRITE(bc ^ 1);
        }
        __syncthreads();            // tile t+1 ready; buf writes visible
    }

    // --- epilogue ---
    lsumA += __shfl_xor(lsumA, 16);
    lsumA += __shfl_xor(lsumA, 32);
    lsumB += __shfl_xor(lsumB, 16);
    lsumB += __shfl_xor(lsumB, 32);
    float invA = 1.f / lsumA;
    float invB = 1.f / lsumB;
    size_t rowA = (size_t)(b * S + wq0 + idx) * 2048 + h * 128;
    size_t rowB = rowA + (size_t)16 * 2048;
    #pragma unroll
    for (int n = 0; n < 8; ++n) {
        ushort4 oA, oB;
        oA.x = f2b(accA[n][0] * invA);
        oA.y = f2b(accA[n][1] * invA);
        oA.z = f2b(accA[n][2] * invA);
        oA.w = f2b(accA[n][3] * invA);
        oB.x = f2b(accB[n][0] * invB);
        oB.y = f2b(accB[n][1] * invB);
        oB.z = f2b(accB[n][2] * invB);
        oB.w = f2b(accB[n][3] * invB);
        *(ushort4*)&out[rowA + n * 16 + quad * 4] = oA;
        *(ushort4*)&out[rowB + n * 16 + quad * 4] = oB;
    }
}

// ---------- launch ----------
extern "C" void kernel_launch(void* const* d_in, const int* in_sizes, int n_in,
                              void* d_out, int out_size, void* d_ws, size_t ws_size,
                              hipStream_t stream)
{
    const float* x  = (const float*)d_in[0];
    const float* fc = (const float*)d_in[1];
    const float* fs = (const float*)d_in[2];
    const float* wq = (const float*)d_in[3];
    const float* wk = (const float*)d_in[4];
    const float* wv = (const float*)d_in[5];
    const float* wo = (const float*)d_in[6];
    float* out = (float*)d_out;

    const int B = 2, S = 2048, D = 2048, KV = 512;
    const int M = B * S;                 // 4096

    unsigned short* ws  = (unsigned short*)d_ws;
    unsigned short* xb  = ws;                         // 4096*2048
    unsigned short* wqb = xb  + (size_t)M * D;        // 2048*2048
    unsigned short* wkb = wqb + (size_t)D * D;        // 512*2048
    unsigned short* wvb = wkb + (size_t)KV * D;       // 512*2048
    unsigned short* wob = wvb + (size_t)KV * D;       // 2048*2048
    unsigned short* qb  = wob + (size_t)D * D;        // 4096*2048
    unsigned short* kb  = qb  + (size_t)M * D;        // 4096*512
    unsigned short* vb  = kb  + (size_t)M * KV;       // 4096*512
    unsigned short* ao  = vb  + (size_t)M * KV;       // 4096*2048

    cvt_f32_to_bf16<<<dim3((M * D / 4) / 256), dim3(256), 0, stream>>>(x,  xb,  M * D / 4);
    cvt_f32_to_bf16<<<dim3((D * D / 4) / 256), dim3(256), 0, stream>>>(wq, wqb, D * D / 4);
    cvt_f32_to_bf16<<<dim3((KV * D / 4) / 256), dim3(256), 0, stream>>>(wk, wkb, KV * D / 4);
    cvt_f32_to_bf16<<<dim3((KV * D / 4) / 256), dim3(256), 0, stream>>>(wv, wvb, KV * D / 4);
    cvt_f32_to_bf16<<<dim3((D * D / 4) / 256), dim3(256), 0, stream>>>(wo, wob, D * D / 4);

    // fused QKV projection: 16 m-tiles x 12 n-tiles = 192 blocks, 512 thr
    qkv_gemm<<<dim3(192), dim3(512), 0, stream>>>(xb, wqb, wkb, wvb, qb, kb, vb);

    int qpairs = B * S * 16 * 64;
    int kpairs = B * S * 4 * 64;
    const float c2 = 0.12752584f;   // (1/sqrt(128)) * log2(e), folded into q
    rope_kernel<<<dim3(qpairs / 256), dim3(256), 0, stream>>>(qb, fc, fs, 16, qpairs, c2);
    rope_kernel<<<dim3(kpairs / 256), dim3(256), 0, stream>>>(kb, fc, fs, 4, kpairs, 1.0f);

    // flash attention: 512 blocks x 256 threads (4 waves, KVBLK=64)
    flash_attn<<<dim3(512), dim3(256), 0, stream>>>(qb, kb, vb, ao);

    gemm_tile<float><<<dim3((M / 128) * (D / 128)), dim3(256), 0, stream>>>(ao, wob, out, M, D, D);
}